// Round 9
// baseline (1195.132 us; speedup 1.0000x reference)
//
#include <hip/hip_runtime.h>

#define NXI 384
#define NG  (NXI*NXI)          // 147456 elements per system
#define NSYS 8
#define BPS 32                 // blocks per system
#define NBLK (NSYS*BPS)        // 256 blocks
#define NTHR 512               // 8 waves/CU
#define ROWS_PB 12             // rows per block
#define EPB (ROWS_PB*NXI)      // 4608 elements per block
#define EPT (EPB/NTHR)         // 9 elements per thread

// thr = EPS*NX*NY = 1e-9*147456
#define THRC 1.47456e-4f

// ---- relaxed agent-scope (fabric-coherent, cache-bypassing) accessors ----
__device__ __forceinline__ float aloadf(const float* p) {
  return __hip_atomic_load(p, __ATOMIC_RELAXED, __HIP_MEMORY_SCOPE_AGENT);
}
__device__ __forceinline__ void astoref(float* p, float v) {
  __hip_atomic_store(p, v, __ATOMIC_RELAXED, __HIP_MEMORY_SCOPE_AGENT);
}
__device__ __forceinline__ double aloadd(const double* p) {
  return __hip_atomic_load(p, __ATOMIC_RELAXED, __HIP_MEMORY_SCOPE_AGENT);
}
__device__ __forceinline__ void astored(double* p, double v) {
  __hip_atomic_store(p, v, __ATOMIC_RELAXED, __HIP_MEMORY_SCOPE_AGENT);
}

__device__ __forceinline__ double wave_red(double v) {
#pragma unroll
  for (int off = 32; off > 0; off >>= 1) v += __shfl_down(v, off, 64);
  return v;
}

// ---- per-system flag barrier: contention-free, no RMW (validated r7/r8) ----
__device__ __forceinline__ void sys_bar(unsigned* flags, unsigned* phase, int tid, int bs) {
  __atomic_signal_fence(__ATOMIC_SEQ_CST);
  __builtin_amdgcn_s_waitcnt(0);   // drain this wave's outstanding stores
  __syncthreads();                 // => ALL waves' stores drained
  const unsigned ph = ++(*phase);
  if (tid == 0) {
    __hip_atomic_store(flags + bs, ph, __ATOMIC_RELAXED, __HIP_MEMORY_SCOPE_AGENT);
  }
  if (tid < 64) {
    while (true) {
      const unsigned f = __hip_atomic_load(flags + (tid & 31), __ATOMIC_RELAXED,
                                           __HIP_MEMORY_SCOPE_AGENT);
      if (__ballot(f >= ph) == ~0ull) break;
      __builtin_amdgcn_s_sleep(1);
    }
  }
  __syncthreads();
  __atomic_signal_fence(__ATOMIC_SEQ_CST);
}

// Block-reduce n<=14 doubles, agent-store to absolute channels [chan0..][..][bs].
__device__ __forceinline__ void bredN(const double* v, int n,
                                      double* slots, int chan0,
                                      int sys, int bs, int tid) {
  __shared__ double sred[NTHR/64][14];
  const int wid = tid >> 6, lane = tid & 63;
  for (int q = 0; q < n; q++) {
    const double w = wave_red(v[q]);
    if (lane == 0) sred[wid][q] = w;
  }
  __syncthreads();
  if (tid == 0) {
    for (int q = 0; q < n; q++) {
      double a = 0.0;
#pragma unroll
      for (int w2 = 0; w2 < NTHR/64; w2++) a += sred[w2][q];
      astored(slots + (size_t)(chan0 + q) * NBLK + sys * BPS + bs, a);
    }
  }
  __syncthreads();
}

// Deterministic butterfly sums of n channels (loads preissued, bit-exact everywhere).
__device__ __forceinline__ void shredN(const double* slots, int chan0, int n,
                                       int sys, int lane, double* out) {
  double v[14];
  for (int q = 0; q < n; q++)
    v[q] = aloadd(slots + (size_t)(chan0 + q) * NBLK + sys * BPS + (lane & 31));
  for (int q = 0; q < n; q++) {
    double x = v[q];
    x += __shfl_xor(x, 1, 64);
    x += __shfl_xor(x, 2, 64);
    x += __shfl_xor(x, 4, 64);
    x += __shfl_xor(x, 8, 64);
    x += __shfl_xor(x, 16, 64);
    out[q] = x;
  }
}

__device__ __forceinline__ float froguard(double sq) {
  return sq > 0.0 ? (float)sqrt(sq) : 0.0f;
}

// ---- coefficient builders (bit-exact shared op sequences) ----
__device__ __forceinline__ float calc_d1b(const float* Vb, const float* M1b, int i, int j) {
  const int a0 = (i - 1 < 0) ? 0 : i - 1;
  const float vc = Vb[j * NXI + i] + 1.0f;
  const float vu = Vb[j * NXI + a0] + 1.0f;
  return M1b[j * NXI + a0] * ((vc - vu) / (0.5f * (vc + vu)));
}
__device__ __forceinline__ float calc_d1a(const float* Vb, const float* M1b, int i, int j) {
  const int a2 = (i + 1 > NXI - 1) ? NXI - 1 : i + 1;
  const float vc = Vb[j * NXI + i] + 1.0f;
  const float vd = Vb[j * NXI + a2] + 1.0f;
  return M1b[j * NXI + i] * ((vd - vc) / (0.5f * (vd + vc)));
}
__device__ __forceinline__ float calc_d2b(const float* Vb, const float* M2b, int i, int j) {
  const int b0 = (j - 1 < 0) ? 0 : j - 1;
  const float vc = Vb[j * NXI + i] + 1.0f;
  const float vl = Vb[b0 * NXI + i] + 1.0f;
  return M2b[b0 * NXI + i] * ((vc - vl) / (0.5f * (vc + vl)));
}
__device__ __forceinline__ float calc_d2a(const float* Vb, const float* M2b, int i, int j) {
  const int b2 = (j + 1 > NXI - 1) ? NXI - 1 : j + 1;
  const float vc = Vb[j * NXI + i] + 1.0f;
  const float vr = Vb[b2 * NXI + i] + 1.0f;
  return M2b[j * NXI + i] * ((vr - vc) / (0.5f * (vr + vc)));
}

// 5-point stencil; coeffs boo/bmo/bom stored (rows -1..12 / -1..13 / -1..12 at
// (r+1)*NXI), bpo/bop derived: bpo(i,j)=-20-bmo(i+1,j), bop(i,j)=-20-bom(i,j+1).
// src slabs span rows -2..13 at (r+2)*NXI. uc read from slab.
__device__ __forceinline__ float applyA(const float* src, int r, int c, int gr,
                                        const float* cboo, const float* cbmo,
                                        const float* cbom) {
  const int ci = (r + 1) * NXI + c;
  const int si = (r + 2) * NXI + c;
  const float uc = src[si];
  const float um = (gr == 0)       ? uc : src[si - NXI];
  const float ud = (gr == NXI - 1) ? uc : src[si + NXI];
  const float ul = (c == 0)        ? uc : src[si - 1];
  const float ur = (c == NXI - 1)  ? uc : src[si + 1];
  const float bpo = (gr < NXI - 1) ? (-20.0f - cbmo[ci + NXI]) : -10.0f;
  const float bop = (c < NXI - 1)  ? (-20.0f - cbom[ci + 1])   : -10.0f;
  return cboo[ci] * uc + cbmo[ci] * um + cbom[ci] * ul + bop * ur + bpo * ud;
}

// rowsum boo+bmo+bom+bop+bpo from stored coeffs (rows -1..12)
__device__ __forceinline__ float coeff_sum_stored(int r, int c, int gr,
    const float* cboo, const float* cbmo, const float* cbom) {
  const int ci = (r + 1) * NXI + c;
  const float bpo = (gr < NXI - 1) ? (-20.0f - cbmo[ci + NXI]) : -10.0f;
  const float bop = (c < NXI - 1)  ? (-20.0f - cbom[ci + 1])   : -10.0f;
  return cboo[ci] + cbmo[ci] + cbom[ci] + bop + bpo;
}
// same rowsum, mirrored op-for-op from V/M (rows -2,13 where nothing is stored)
__device__ __forceinline__ float coeff_sum_direct(const float* Vb, const float* M1b,
                                                  const float* M2b, int gr, int c) {
  const float d1b = calc_d1b(Vb, M1b, gr, c);
  const float d1a = calc_d1a(Vb, M1b, gr, c);
  const float d2b = calc_d2b(Vb, M2b, gr, c);
  const float d2a = calc_d2a(Vb, M2b, gr, c);
  const float boo = 41.0f - 5.0f * (d1b - d1a) - 5.0f * (d2b - d2a);
  const float bmo = -10.0f - 5.0f * d1b;
  const float bom = -10.0f - 5.0f * d2b;
  float bpo;
  if (gr < NXI - 1) {
    const float bmon = -10.0f - 5.0f * calc_d1b(Vb, M1b, gr + 1, c);
    bpo = -20.0f - bmon;
  } else bpo = -10.0f;
  float bop;
  if (c < NXI - 1) {
    const float bomn = -10.0f - 5.0f * calc_d2b(Vb, M2b, gr, c + 1);
    bop = -20.0f - bomn;
  } else bop = -10.0f;
  return boo + bmo + bom + bop + bpo;
}

__global__ __launch_bounds__(NTHR, 1) void bicg_kernel(
    const float* __restrict__ V, const float* __restrict__ M1, const float* __restrict__ M2,
    float* __restrict__ xout, float* __restrict__ wsf) {
  const int blk = blockIdx.x;
  const int sys = blk & (NSYS - 1);
  const int bs  = blk >> 3;
  const int tid = threadIdx.x;
  const int lane = tid & 63;
  const int gr0 = bs * ROWS_PB;

  // ---- LDS (152.96 KB total) ----
  __shared__ float slabP[16 * NXI];     // p rows -2..13
  __shared__ float slabR[16 * NXI];     // r rows -2..13 (x staging in restart via slabV)
  __shared__ float slabV[16 * NXI];     // v rows -2..13
  __shared__ float cboo[14 * NXI];      // rows -1..12
  __shared__ float cbmo[15 * NXI];      // rows -1..13
  __shared__ float cbom[14 * NXI];      // rows -1..12
  __shared__ float zbuf[4 * NXI];       // z rows -2,-1,12,13
  __shared__ float wbuf[4 * NXI];       // w rows -2,-1,12,13

  // ---- workspace ----
  unsigned* flags = (unsigned*)wsf + sys * 32;          // memset 0
  double* slots = (double*)(wsf + 1024);                // byte 4096: 32 chans * 256
  const size_t PSZ = (size_t)NSYS * BPS * 2 * NXI;      // one parity buffer
  float* gbase = wsf + 32768;                            // byte 131072
  float* ghv = gbase;                                    // [2(par)][sys][bs][2][NXI]
  float* ghz = ghv + 2 * PSZ;
  float* ghw = ghz + 2 * PSZ;
  float* ghx = ghw + 2 * PSZ;                            // [sys][bs][2][NXI] restart x
  float* ghq = ghx + PSZ;                                // [sys][bs][4][NXI] restart p
  float* ghx_sys = ghx + (size_t)sys * BPS * 2 * NXI;
  float* ghq_sys = ghq + (size_t)sys * BPS * 4 * NXI;
  float* ghx_own = ghx_sys + (size_t)bs * 2 * NXI;
  float* ghq_own = ghq_sys + (size_t)bs * 4 * NXI;

  unsigned bphase = 0;

  const size_t so = (size_t)sys * NG;
  const float* Vb  = V  + so;
  const float* M1b = M1 + so;
  const float* M2b = M2 + so;
  float* xs = xout + so + (size_t)bs * EPB;

  // ---------- Phase 0: coefficients (rows -1..13) + V-mean partial ----------
  for (int q = tid; q < 15 * NXI; q += NTHR) {
    const int r = q / NXI - 1;                 // -1..13
    const int gr = gr0 + r;
    if ((unsigned)gr >= (unsigned)NXI) continue;
    const int c = q - (r + 1) * NXI;
    const float d1b = calc_d1b(Vb, M1b, gr, c);
    cbmo[q] = -10.0f - 5.0f * d1b;
    if (r <= 12) {
      const float d1a = calc_d1a(Vb, M1b, gr, c);
      const float d2b = calc_d2b(Vb, M2b, gr, c);
      const float d2a = calc_d2a(Vb, M2b, gr, c);
      cboo[q] = 41.0f - 5.0f * (d1b - d1a) - 5.0f * (d2b - d2a);
      cbom[q] = -10.0f - 5.0f * d2b;
    }
  }
  {
    double vsum = 0.0;
#pragma unroll
    for (int k = 0; k < EPT; k++) vsum += (double)Vb[bs * EPB + tid + k * NTHR];
    double d0[1] = {vsum};
    bredN(d0, 1, slots, 31, sys, bs, tid);
  }
  sys_bar(flags, &bphase, tid, bs);  // S0 (the only setup barrier)

  // ---------- Init: x=mb; p=r=r0 = mb - rowsum*mb on own + ghost rows ----------
  double smb[1]; shredN(slots, 31, 1, sys, lane, smb);
  const float mb = (float)(smb[0] / (double)NG) + 1.0f;
  float preg[EPT], rreg[EPT], r0reg[EPT], vreg[EPT], zreg[EPT], wreg[EPT], xreg[EPT];
#pragma unroll
  for (int k = 0; k < EPT; k++) {
    const int e = tid + k * NTHR;
    const int lr = e / NXI, c = e - lr * NXI;
    const int gr = gr0 + lr;
    const float pn = mb - coeff_sum_stored(lr, c, gr, cboo, cbmo, cbom) * mb;
    xreg[k] = mb;
    preg[k] = pn; rreg[k] = pn; r0reg[k] = pn;
    slabP[(lr + 2) * NXI + c] = pn;
    slabR[(lr + 2) * NXI + c] = pn;
  }
  for (int g = tid; g < 4 * NXI; g += NTHR) {
    const int gi = g / NXI, c = g - gi * NXI;
    const int r = (gi < 2) ? gi - 2 : gi + 10;      // -2,-1,12,13
    if ((r < 0) ? (bs > 0) : (bs < BPS - 1)) {
      const int gr = gr0 + r;
      const float rs = (r == -2 || r == 13)
          ? coeff_sum_direct(Vb, M1b, M2b, gr, c)
          : coeff_sum_stored(r, c, gr, cboo, cbmo, cbom);
      const float pn = mb - rs * mb;
      slabP[(r + 2) * NXI + c] = pn;
      slabR[(r + 2) * NXI + c] = pn;
    }
  }
  float r0_abs = 0.f, r_abs = 1.0f;   // dummy > thr to enter it=0
  float alpha = 0.f, omega = 0.f, rho = 0.f;

  for (int it = 0; it < 30; ++it) {
    if (!(r_abs > THRC)) break;      // uniform within system
    const int par = it & 1;
    float* ghv_sys = ghv + (size_t)par * PSZ + (size_t)sys * BPS * 2 * NXI;
    float* ghz_sys = ghz + (size_t)par * PSZ + (size_t)sys * BPS * 2 * NXI;
    float* ghw_sys = ghw + (size_t)par * PSZ + (size_t)sys * BPS * 2 * NXI;
    float* ghv_own = ghv_sys + (size_t)bs * 2 * NXI;  // [0]=row1, [NXI]=row10
    float* ghz_own = ghz_sys + (size_t)bs * 2 * NXI;
    float* ghw_own = ghw_sys + (size_t)bs * 2 * NXI;
    const int ch0 = par * 14;                          // dot channels 0..27
    __syncthreads();   // P3 slab writes from prev iter visible

    // ==== P1: v=Ap (own + ghost -1,12); z=Ar, w=Av own; z ghosts; 14 dots ====
    double d[14] = {0,0,0,0,0,0,0,0,0,0,0,0,0,0};
#pragma unroll
    for (int k = 0; k < EPT; k++) {
      const int e = tid + k * NTHR;
      const int lr = e / NXI, c = e - lr * NXI;
      const int gr = gr0 + lr;
      const float vv = applyA(slabP, lr, c, gr, cboo, cbmo, cbom);
      vreg[k] = vv;
      slabV[(lr + 2) * NXI + c] = vv;
      if (lr == 1)  astoref(ghv_own + c, vv);
      if (lr == 10) astoref(ghv_own + NXI + c, vv);
      d[0] += (double)vv * (double)r0reg[k];
      d[1] += (double)vv * (double)vv;
      d[2] += (double)rreg[k] * (double)r0reg[k];
      d[3] += (double)rreg[k] * (double)vv;
      d[4] += (double)rreg[k] * (double)rreg[k];
    }
    for (int g = tid; g < 2 * NXI; g += NTHR) {      // v ghosts rows -1,12
      const bool top = g < NXI;
      if (top ? (bs > 0) : (bs < BPS - 1)) {
        const int c = top ? g : g - NXI;
        const int r = top ? -1 : 12;
        slabV[(r + 2) * NXI + c] = applyA(slabP, r, c, gr0 + r, cboo, cbmo, cbom);
      }
    }
    __syncthreads();
#pragma unroll
    for (int k = 0; k < EPT; k++) {
      const int e = tid + k * NTHR;
      const int lr = e / NXI, c = e - lr * NXI;
      const int gr = gr0 + lr;
      const float zz = applyA(slabR, lr, c, gr, cboo, cbmo, cbom);
      const float ww = applyA(slabV, lr, c, gr, cboo, cbmo, cbom);
      zreg[k] = zz; wreg[k] = ww;
      if (lr == 1)  { astoref(ghz_own + c, zz);        astoref(ghw_own + c, ww); }
      if (lr == 10) { astoref(ghz_own + NXI + c, zz);  astoref(ghw_own + NXI + c, ww); }
      d[5]  += (double)zz * (double)zz;
      d[6]  += (double)zz * (double)ww;
      d[7]  += (double)ww * (double)ww;
      d[8]  += (double)zz * (double)rreg[k];
      d[9]  += (double)zz * (double)vreg[k];
      d[10] += (double)ww * (double)rreg[k];
      d[11] += (double)ww * (double)vreg[k];
      d[12] += (double)zz * (double)r0reg[k];
      d[13] += (double)ww * (double)r0reg[k];
    }
    for (int g = tid; g < 2 * NXI; g += NTHR) {      // z ghosts rows -1,12
      const bool top = g < NXI;
      if (top ? (bs > 0) : (bs < BPS - 1)) {
        const int c = top ? g : g - NXI;
        const int r = top ? -1 : 12;
        zbuf[(top ? 1 : 2) * NXI + c] = applyA(slabR, r, c, gr0 + r, cboo, cbmo, cbom);
      }
    }
    bredN(d, 14, slots, ch0, sys, bs, tid);
    sys_bar(flags, &bphase, tid, bs);  // THE barrier

    // ==== P2/P3: receive ghosts; all scalars; branches; update everything ====
    for (int g = tid; g < 2 * NXI; g += NTHR) {      // receive v,z,w rows -2,13
      const bool top = g < NXI;
      const int c = top ? g : g - NXI;
      if (top) { if (bs > 0) {
        const size_t nb = (size_t)(bs - 1) * 2 * NXI;
        slabV[c] = aloadf(ghv_sys + nb + NXI + c);
        zbuf[c]  = aloadf(ghz_sys + nb + NXI + c);
        wbuf[c]  = aloadf(ghw_sys + nb + NXI + c);
      }} else { if (bs < BPS - 1) {
        const size_t nb = (size_t)(bs + 1) * 2 * NXI;
        slabV[15 * NXI + c] = aloadf(ghv_sys + nb + c);
        zbuf[3 * NXI + c]   = aloadf(ghz_sys + nb + c);
        wbuf[3 * NXI + c]   = aloadf(ghw_sys + nb + c);
      }}
    }
    double s[14];
    shredN(slots, ch0, 14, sys, lane, s);
    const float sigma = (float)s[0];
    const float v_abs = froguard(s[1]);
    rho = (float)s[2];
    if (it == 0) {
      r0_abs = froguard(s[4]);
      r_abs = r0_abs;
      if (!(r_abs > THRC)) break;    // converged at init; x stays mb
    }
    const bool RES = (sigma <= 1e-9f * v_abs * r0_abs);  // uniform

    if (RES) {
      // restart: p=r=r0 = mb - A x (explicit 1-row x exchange, then p depth-2)
      __syncthreads();
#pragma unroll
      for (int k = 0; k < EPT; k++) {
        const int e = tid + k * NTHR;
        const int lr = e / NXI, c = e - lr * NXI;
        slabV[(lr + 2) * NXI + c] = xreg[k];
        if (lr == 0)  astoref(ghx_own + c, xreg[k]);
        if (lr == 11) astoref(ghx_own + NXI + c, xreg[k]);
      }
      sys_bar(flags, &bphase, tid, bs);  // R1
      for (int g = tid; g < 2 * NXI; g += NTHR) {
        const bool top = g < NXI;
        const int c = top ? g : g - NXI;
        if (top) { if (bs > 0)       slabV[1 * NXI + c]  = aloadf(ghx_sys + (size_t)(bs - 1) * 2 * NXI + NXI + c); }
        else     { if (bs < BPS - 1) slabV[14 * NXI + c] = aloadf(ghx_sys + (size_t)(bs + 1) * 2 * NXI + c); }
      }
      __syncthreads();
      double pp = 0;
#pragma unroll
      for (int k = 0; k < EPT; k++) {
        const int e = tid + k * NTHR;
        const int lr = e / NXI, c = e - lr * NXI;
        const int gr = gr0 + lr;
        const float pn = mb - applyA(slabV, lr, c, gr, cboo, cbmo, cbom);
        preg[k] = pn; rreg[k] = pn; r0reg[k] = pn;
        slabP[(lr + 2) * NXI + c] = pn;
        slabR[(lr + 2) * NXI + c] = pn;
        if (lr == 0)  astoref(ghq_own + c, pn);
        if (lr == 1)  astoref(ghq_own + NXI + c, pn);
        if (lr == 10) astoref(ghq_own + 2 * NXI + c, pn);
        if (lr == 11) astoref(ghq_own + 3 * NXI + c, pn);
        pp += (double)pn * (double)pn;
      }
      { double d1[1] = {pp}; bredN(d1, 1, slots, 28 + par, sys, bs, tid); }
      sys_bar(flags, &bphase, tid, bs);  // R2
      for (int g = tid; g < 4 * NXI; g += NTHR) {
        const int gi = g / NXI, c = g - gi * NXI;
        const int r = (gi < 2) ? gi - 2 : gi + 10;
        if ((r < 0) ? (bs > 0) : (bs < BPS - 1)) {
          float pn;
          if (gi == 0)      pn = aloadf(ghq_sys + (size_t)(bs - 1) * 4 * NXI + 2 * NXI + c);
          else if (gi == 1) pn = aloadf(ghq_sys + (size_t)(bs - 1) * 4 * NXI + 3 * NXI + c);
          else if (gi == 2) pn = aloadf(ghq_sys + (size_t)(bs + 1) * 4 * NXI + c);
          else              pn = aloadf(ghq_sys + (size_t)(bs + 1) * 4 * NXI + NXI + c);
          slabP[(r + 2) * NXI + c] = pn;
          slabR[(r + 2) * NXI + c] = pn;
        }
      }
      double spp[1]; shredN(slots, 28 + par, 1, sys, lane, spp);
      r0_abs = froguard(spp[0]);
      r_abs = r0_abs;
      continue;
    }

    alpha = rho / sigma;
    const double da = (double)alpha;
    const double ss2 = s[4] - 2.0 * da * s[3] + da * da * s[1];  // <s,s>
    const float s_abs = froguard(ss2);

    if (s_abs <= THRC) {
      // C3: x += alpha*p ; r = s (terminal)
#pragma unroll
      for (int k = 0; k < EPT; k++) {
        xreg[k] = xreg[k] + alpha * preg[k];
        rreg[k] = rreg[k] - alpha * vreg[k];
      }
      r_abs = s_abs;
      continue;
    }

    const double tt_d  = s[5] - 2.0 * da * s[6] + da * da * s[7];
    const double ts_d  = s[8] - da * s[9] - da * s[10] + da * da * s[11];
    const double sr0_d = s[2] - da * s[0];
    const double tr0_d = s[12] - da * s[13];
    omega = (float)ts_d / (float)tt_d;
    const double dw = (double)omega;
    const float rho_new = (float)(sr0_d - dw * tr0_d);
    const double rr_new = ss2 - 2.0 * dw * ts_d + dw * dw * tt_d;
    const float beta = (alpha / omega) * (rho_new / rho);

    __syncthreads();   // received slabV rows -2,13 visible before w-ghost compute
    for (int g = tid; g < 2 * NXI; g += NTHR) {      // w ghosts rows -1,12 (local)
      const bool top = g < NXI;
      if (top ? (bs > 0) : (bs < BPS - 1)) {
        const int c = top ? g : g - NXI;
        const int r = top ? -1 : 12;
        wbuf[(top ? 1 : 2) * NXI + c] = applyA(slabV, r, c, gr0 + r, cboo, cbmo, cbom);
      }
    }
    __syncthreads();   // wbuf visible before ghost maintenance

    // own-row updates (t = z - alpha*w elementwise; exact recombination of A s)
#pragma unroll
    for (int k = 0; k < EPT; k++) {
      const int e = tid + k * NTHR;
      const int lr = e / NXI, c = e - lr * NXI;
      const float sc = rreg[k] - alpha * vreg[k];
      xreg[k] = xreg[k] + alpha * preg[k] + omega * sc;
      const float tn = zreg[k] - alpha * wreg[k];
      const float rn = sc - omega * tn;
      const float pn = rn + beta * (preg[k] - omega * vreg[k]);
      rreg[k] = rn;
      preg[k] = pn;
      slabR[(lr + 2) * NXI + c] = rn;
      slabP[(lr + 2) * NXI + c] = pn;
    }
    // ghost maintenance rows -2,-1,12,13 (bit-identical to neighbors' own rows)
    for (int g = tid; g < 4 * NXI; g += NTHR) {
      const int gi = g / NXI, c = g - gi * NXI;
      const int r = (gi < 2) ? gi - 2 : gi + 10;
      if ((r < 0) ? (bs > 0) : (bs < BPS - 1)) {
        const int ci = (r + 2) * NXI + c;
        const float rg = slabR[ci];
        const float vg = slabV[ci];
        const float sg = rg - alpha * vg;
        const float tg = zbuf[gi * NXI + c] - alpha * wbuf[gi * NXI + c];
        const float rgn = sg - omega * tg;
        const float pgn = rgn + beta * (slabP[ci] - omega * vg);
        slabR[ci] = rgn;
        slabP[ci] = pgn;
      }
    }
    r_abs = froguard(rr_new);
    // no barrier: next P1 reads only block-local LDS (loop-top __syncthreads)
  }

  // final write-out of x
#pragma unroll
  for (int k = 0; k < EPT; k++) {
    xs[tid + k * NTHR] = xreg[k];
  }
}

extern "C" void kernel_launch(void* const* d_in, const int* in_sizes, int n_in,
                              void* d_out, int out_size, void* d_ws, size_t ws_size,
                              hipStream_t stream) {
  const float* V  = (const float*)d_in[0];
  const float* M1 = (const float*)d_in[1];
  const float* M2 = (const float*)d_in[2];
  float* xout = (float*)d_out;
  float* wsf  = (float*)d_ws;
  // zero the per-system flag arrays (ws is re-poisoned each call)
  hipMemsetAsync(d_ws, 0, 4096, stream);
  bicg_kernel<<<dim3(NBLK), dim3(NTHR), 0, stream>>>(V, M1, M2, xout, wsf);
}

// Round 10
// 720.425 us; speedup vs baseline: 1.6589x; 1.6589x over previous
//
#include <hip/hip_runtime.h>

#define NXI 384
#define NG  (NXI*NXI)          // 147456 elements per system
#define NSYS 8
#define BPS 32                 // blocks per system
#define NBLK (NSYS*BPS)        // 256 blocks
#define NTHR 512               // 8 waves/CU
#define ROWS_PB 12             // rows per block
#define EPB (ROWS_PB*NXI)      // 4608 elements per block
#define EPT (EPB/NTHR)         // 9 elements per thread

// thr = EPS*NX*NY = 1e-9*147456
#define THRC 1.47456e-4f

// ---- relaxed agent-scope accessors ----
__device__ __forceinline__ float aloadf(const float* p) {
  return __hip_atomic_load(p, __ATOMIC_RELAXED, __HIP_MEMORY_SCOPE_AGENT);
}
__device__ __forceinline__ void astoref(float* p, float v) {
  __hip_atomic_store(p, v, __ATOMIC_RELAXED, __HIP_MEMORY_SCOPE_AGENT);
}
__device__ __forceinline__ double aloadd(const double* p) {
  return __hip_atomic_load(p, __ATOMIC_RELAXED, __HIP_MEMORY_SCOPE_AGENT);
}
__device__ __forceinline__ void astored(double* p, double v) {
  __hip_atomic_store(p, v, __ATOMIC_RELAXED, __HIP_MEMORY_SCOPE_AGENT);
}

__device__ __forceinline__ double wave_red(double v) {
#pragma unroll
  for (int off = 32; off > 0; off >>= 1) v += __shfl_down(v, off, 64);
  return v;
}

// ---- per-system flag barrier: contention-free, no RMW (validated r7-r9) ----
__device__ __forceinline__ void sys_bar(unsigned* flags, unsigned* phase, int tid, int bs) {
  __atomic_signal_fence(__ATOMIC_SEQ_CST);
  __builtin_amdgcn_s_waitcnt(0);
  __syncthreads();
  const unsigned ph = ++(*phase);
  if (tid == 0) {
    __hip_atomic_store(flags + bs, ph, __ATOMIC_RELAXED, __HIP_MEMORY_SCOPE_AGENT);
  }
  if (tid < 64) {
    while (true) {
      const unsigned f = __hip_atomic_load(flags + (tid & 31), __ATOMIC_RELAXED,
                                           __HIP_MEMORY_SCOPE_AGENT);
      if (__ballot(f >= ph) == ~0ull) break;
      __builtin_amdgcn_s_sleep(1);
    }
  }
  __syncthreads();
  __atomic_signal_fence(__ATOMIC_SEQ_CST);
}

// Block-reduce n<=9 doubles, agent-store to channels [chan0..][sys][bs].
__device__ __forceinline__ void bredN(const double* v, int n,
                                      double* slots, int chan0,
                                      int sys, int bs, int tid) {
  __shared__ double sred[NTHR/64][9];
  const int wid = tid >> 6, lane = tid & 63;
#pragma unroll
  for (int q = 0; q < n; q++) {
    const double w = wave_red(v[q]);
    if (lane == 0) sred[wid][q] = w;
  }
  __syncthreads();
  if (tid == 0) {
#pragma unroll
    for (int q = 0; q < n; q++) {
      double a = 0.0;
#pragma unroll
      for (int w2 = 0; w2 < NTHR/64; w2++) a += sred[w2][q];
      astored(slots + (size_t)(chan0 + q) * NBLK + sys * BPS + bs, a);
    }
  }
  __syncthreads();
}

// Butterfly sums of n channels (bit-exact identical in every lane/block).
__device__ __forceinline__ void shredN(const double* slots, int chan0, int n,
                                       int sys, int lane, double* out) {
  double v[14];
#pragma unroll
  for (int q = 0; q < n; q++)
    v[q] = aloadd(slots + (size_t)(chan0 + q) * NBLK + sys * BPS + (lane & 31));
#pragma unroll
  for (int q = 0; q < n; q++) {
    double x = v[q];
    x += __shfl_xor(x, 1, 64);
    x += __shfl_xor(x, 2, 64);
    x += __shfl_xor(x, 4, 64);
    x += __shfl_xor(x, 8, 64);
    x += __shfl_xor(x, 16, 64);
    out[q] = x;
  }
}

__device__ __forceinline__ float froguard(double sq) {
  return sq > 0.0 ? (float)sqrt(sq) : 0.0f;
}

// ---- coefficient builders (bit-exact shared op sequences) ----
__device__ __forceinline__ float calc_d1b(const float* Vb, const float* M1b, int i, int j) {
  const int a0 = (i - 1 < 0) ? 0 : i - 1;
  const float vc = Vb[j * NXI + i] + 1.0f;
  const float vu = Vb[j * NXI + a0] + 1.0f;
  return M1b[j * NXI + a0] * ((vc - vu) / (0.5f * (vc + vu)));
}
__device__ __forceinline__ float calc_d2b(const float* Vb, const float* M2b, int i, int j) {
  const int b0 = (j - 1 < 0) ? 0 : j - 1;
  const float vc = Vb[j * NXI + i] + 1.0f;
  const float vl = Vb[b0 * NXI + i] + 1.0f;
  return M2b[b0 * NXI + i] * ((vc - vl) / (0.5f * (vc + vl)));
}

// 5-point stencil. Coeffs: bmo rows -1..13, bom rows -1..12 at (r+1)*NXI.
// Derived: bpo(i,j)=-20-bmo(i+1,j) (or -10 at i=383); bop(i,j)=-20-bom(i,j+1)
// (or -10 at j=383); boo = 81 + bmo + bom + bpo + bop (exact identities of the
// reference build). src slabs span rows -2..13 at (r+2)*NXI.
__device__ __forceinline__ float applyA(const float* src, int r, int c, int gr,
                                        const float* cbmo, const float* cbom) {
  const int ci = (r + 1) * NXI + c;
  const int si = (r + 2) * NXI + c;
  const float uc = src[si];
  const float um = (gr == 0)       ? uc : src[si - NXI];
  const float ud = (gr == NXI - 1) ? uc : src[si + NXI];
  const float ul = (c == 0)        ? uc : src[si - 1];
  const float ur = (c == NXI - 1)  ? uc : src[si + 1];
  const float bmo = cbmo[ci], bom = cbom[ci];
  const float bpo = (gr < NXI - 1) ? (-20.0f - cbmo[ci + NXI]) : -10.0f;
  const float bop = (c < NXI - 1)  ? (-20.0f - cbom[ci + 1])   : -10.0f;
  const float boo = 81.0f + bmo + bom + bpo + bop;
  return boo * uc + bmo * um + bom * ul + bop * ur + bpo * ud;
}

// rowsum from stored coeffs (rows -1..12)
__device__ __forceinline__ float coeff_sum_stored(int r, int c, int gr,
                                                  const float* cbmo, const float* cbom) {
  const int ci = (r + 1) * NXI + c;
  const float bmo = cbmo[ci], bom = cbom[ci];
  const float bpo = (gr < NXI - 1) ? (-20.0f - cbmo[ci + NXI]) : -10.0f;
  const float bop = (c < NXI - 1)  ? (-20.0f - cbom[ci + 1])   : -10.0f;
  const float boo = 81.0f + bmo + bom + bpo + bop;
  return boo + bmo + bom + bpo + bop;
}
// same rowsum mirrored op-for-op from V/M (rows -2,13; validated in r9)
__device__ __forceinline__ float coeff_sum_direct(const float* Vb, const float* M1b,
                                                  const float* M2b, int gr, int c) {
  const float bmo = -10.0f - 5.0f * calc_d1b(Vb, M1b, gr, c);
  const float bom = -10.0f - 5.0f * calc_d2b(Vb, M2b, gr, c);
  float bpo;
  if (gr < NXI - 1) {
    const float bmon = -10.0f - 5.0f * calc_d1b(Vb, M1b, gr + 1, c);
    bpo = -20.0f - bmon;
  } else bpo = -10.0f;
  float bop;
  if (c < NXI - 1) {
    const float bomn = -10.0f - 5.0f * calc_d2b(Vb, M2b, gr, c + 1);
    bop = -20.0f - bomn;
  } else bop = -10.0f;
  const float boo = 81.0f + bmo + bom + bpo + bop;
  return boo + bmo + bom + bpo + bop;
}

__global__ __launch_bounds__(NTHR, 1) void bicg_kernel(
    const float* __restrict__ V, const float* __restrict__ M1, const float* __restrict__ M2,
    float* __restrict__ xout, float* __restrict__ wsf) {
  const int blk = blockIdx.x;
  const int sys = blk & (NSYS - 1);
  const int bs  = blk >> 3;
  const int tid = threadIdx.x;
  const int lane = tid & 63;
  const int gr0 = bs * ROWS_PB;

  // ---- LDS (~131 KB) ----
  __shared__ float slabP[16 * NXI];     // p rows -2..13
  __shared__ float slabR[16 * NXI];     // r rows -2..13 (x staging via slabV in restart)
  __shared__ float slabV[16 * NXI];     // v rows -2..13
  __shared__ float cbmo[15 * NXI];      // rows -1..13
  __shared__ float cbom[14 * NXI];      // rows -1..12
  __shared__ float zbuf[4 * NXI];       // z rows -2,-1,12,13
  __shared__ float wbuf[4 * NXI];       // w rows -2,-1,12,13
  __shared__ float bcf[4];              // 0:alpha 1:omega 2:beta 3:r_abs
  __shared__ int   bci[1];              // branch code: 0 normal 1 RES 2 C3 3 SKIP
  __shared__ float sh_r0abs;            // wave-0 private persistent r0_abs

  // ---- workspace ----
  unsigned* flags = (unsigned*)wsf + sys * 32;
  double* slots = (double*)(wsf + 1024);                // 32 chans * 256 doubles
  const size_t PSZ = (size_t)NSYS * BPS * 2 * NXI;
  float* gbase = wsf + 32768;
  float* ghv = gbase;                                    // [2][sys][bs][2][NXI]
  float* ghz = ghv + 2 * PSZ;
  float* ghw = ghz + 2 * PSZ;
  float* ghx = ghw + 2 * PSZ;                            // restart x halos
  float* ghq = ghx + PSZ;                                // restart p halos [sys][bs][4][NXI]
  float* ghx_sys = ghx + (size_t)sys * BPS * 2 * NXI;
  float* ghq_sys = ghq + (size_t)sys * BPS * 4 * NXI;
  float* ghx_own = ghx_sys + (size_t)bs * 2 * NXI;
  float* ghq_own = ghq_sys + (size_t)bs * 4 * NXI;

  unsigned bphase = 0;

  const size_t so = (size_t)sys * NG;
  const float* Vb  = V  + so;
  const float* M1b = M1 + so;
  const float* M2b = M2 + so;
  float* xs = xout + so + (size_t)bs * EPB;

  // ---------- Phase 0: coefficients + V-mean partial ----------
  for (int q = tid; q < 15 * NXI; q += NTHR) {
    const int r = q / NXI - 1;                 // -1..13
    const int gr = gr0 + r;
    if ((unsigned)gr >= (unsigned)NXI) continue;
    const int c = q - (r + 1) * NXI;
    cbmo[q] = -10.0f - 5.0f * calc_d1b(Vb, M1b, gr, c);
    if (r <= 12) cbom[q] = -10.0f - 5.0f * calc_d2b(Vb, M2b, gr, c);
  }
  {
    double vsum = 0.0;
#pragma unroll
    for (int k = 0; k < EPT; k++) vsum += (double)Vb[bs * EPB + tid + k * NTHR];
    bredN(&vsum, 1, slots, 31, sys, bs, tid);
  }
  sys_bar(flags, &bphase, tid, bs);  // S0

  // ---------- Init: x=mb; p=r=r0 = mb - rowsum*mb (own + ghost rows) ----------
  double smb[1]; shredN(slots, 31, 1, sys, lane, smb);
  const float mb = (float)(smb[0] / (double)NG) + 1.0f;
  float preg[EPT], rreg[EPT], r0reg[EPT], vreg[EPT], zreg[EPT], wreg[EPT], xreg[EPT];
#pragma unroll
  for (int k = 0; k < EPT; k++) {
    const int e = tid + k * NTHR;
    const int lr = e / NXI, c = e - lr * NXI;
    const float pn = mb - coeff_sum_stored(lr, c, gr0 + lr, cbmo, cbom) * mb;
    xreg[k] = mb;
    preg[k] = pn; rreg[k] = pn; r0reg[k] = pn;
    slabP[(lr + 2) * NXI + c] = pn;
    slabR[(lr + 2) * NXI + c] = pn;
  }
  for (int g = tid; g < 4 * NXI; g += NTHR) {
    const int gi = g / NXI, c = g - gi * NXI;
    const int r = (gi < 2) ? gi - 2 : gi + 10;      // -2,-1,12,13
    if ((r < 0) ? (bs > 0) : (bs < BPS - 1)) {
      const int gr = gr0 + r;
      const float rs = (r == -2 || r == 13)
          ? coeff_sum_direct(Vb, M1b, M2b, gr, c)
          : coeff_sum_stored(r, c, gr, cbmo, cbom);
      const float pn = mb - rs * mb;
      slabP[(r + 2) * NXI + c] = pn;
      slabR[(r + 2) * NXI + c] = pn;
    }
  }
  if (tid == 0) { bcf[3] = 1.0f; bci[0] = 0; }   // enter it=0

  for (int it = 0; it < 30; ++it) {
    __syncthreads();                 // bc + slab writes visible
    if (!(bcf[3] > THRC)) break;     // uniform (LDS broadcast)
    const int par = it & 1;
    float* ghv_sys = ghv + (size_t)par * PSZ + (size_t)sys * BPS * 2 * NXI;
    float* ghz_sys = ghz + (size_t)par * PSZ + (size_t)sys * BPS * 2 * NXI;
    float* ghw_sys = ghw + (size_t)par * PSZ + (size_t)sys * BPS * 2 * NXI;
    float* ghv_own = ghv_sys + (size_t)bs * 2 * NXI;  // [0]=row1, [NXI]=row10
    float* ghz_own = ghz_sys + (size_t)bs * 2 * NXI;
    float* ghw_own = ghw_sys + (size_t)bs * 2 * NXI;
    const int ch0 = par * 14;

    // ==== P1 pass A: v = A p (own + ghost -1,12); 5 dots ====
    {
      double d[5] = {0, 0, 0, 0, 0};
#pragma unroll
      for (int k = 0; k < EPT; k++) {
        const int e = tid + k * NTHR;
        const int lr = e / NXI, c = e - lr * NXI;
        const float vv = applyA(slabP, lr, c, gr0 + lr, cbmo, cbom);
        vreg[k] = vv;
        slabV[(lr + 2) * NXI + c] = vv;
        if (lr == 1)  astoref(ghv_own + c, vv);
        if (lr == 10) astoref(ghv_own + NXI + c, vv);
        d[0] += (double)vv * (double)r0reg[k];
        d[1] += (double)vv * (double)vv;
        d[2] += (double)rreg[k] * (double)r0reg[k];
        d[3] += (double)rreg[k] * (double)vv;
        d[4] += (double)rreg[k] * (double)rreg[k];
      }
      for (int g = tid; g < 2 * NXI; g += NTHR) {      // v ghosts rows -1,12
        const bool top = g < NXI;
        if (top ? (bs > 0) : (bs < BPS - 1)) {
          const int c = top ? g : g - NXI;
          const int r = top ? -1 : 12;
          slabV[(r + 2) * NXI + c] = applyA(slabP, r, c, gr0 + r, cbmo, cbom);
        }
      }
      bredN(d, 5, slots, ch0, sys, bs, tid);   // internal syncthreads = passA->B sync
    }
    // ==== P1 pass B: z = A r, w = A v (own); z ghosts; 9 dots ====
    {
      double d[9] = {0, 0, 0, 0, 0, 0, 0, 0, 0};
#pragma unroll
      for (int k = 0; k < EPT; k++) {
        const int e = tid + k * NTHR;
        const int lr = e / NXI, c = e - lr * NXI;
        const int gr = gr0 + lr;
        const float zz = applyA(slabR, lr, c, gr, cbmo, cbom);
        const float ww = applyA(slabV, lr, c, gr, cbmo, cbom);
        zreg[k] = zz; wreg[k] = ww;
        if (lr == 1)  { astoref(ghz_own + c, zz);       astoref(ghw_own + c, ww); }
        if (lr == 10) { astoref(ghz_own + NXI + c, zz); astoref(ghw_own + NXI + c, ww); }
        d[0] += (double)zz * (double)zz;
        d[1] += (double)zz * (double)ww;
        d[2] += (double)ww * (double)ww;
        d[3] += (double)zz * (double)rreg[k];
        d[4] += (double)zz * (double)vreg[k];
        d[5] += (double)ww * (double)rreg[k];
        d[6] += (double)ww * (double)vreg[k];
        d[7] += (double)zz * (double)r0reg[k];
        d[8] += (double)ww * (double)r0reg[k];
      }
      for (int g = tid; g < 2 * NXI; g += NTHR) {      // z ghosts rows -1,12 (local)
        const bool top = g < NXI;
        if (top ? (bs > 0) : (bs < BPS - 1)) {
          const int c = top ? g : g - NXI;
          const int r = top ? -1 : 12;
          zbuf[(top ? 1 : 2) * NXI + c] = applyA(slabR, r, c, gr0 + r, cbmo, cbom);
        }
      }
      bredN(d, 9, slots, ch0 + 5, sys, bs, tid);
    }
    sys_bar(flags, &bphase, tid, bs);  // THE barrier

    // ==== post-barrier: wave0 scalars -> LDS; waves 1-7 receive ghosts ====
    if (tid < 64) {
      double s[14];
      shredN(slots, ch0, 14, sys, lane, s);
      const float sigma = (float)s[0];
      const float v_abs = froguard(s[1]);
      const float rho_l = (float)s[2];
      const float r0a = (it == 0) ? froguard(s[4]) : sh_r0abs;
      int code = 0;
      float al = 0.f, om = 0.f, be = 0.f, ra = 0.f;
      if (it == 0 && !(r0a > THRC)) {
        code = 3; ra = r0a;
      } else if (sigma <= 1e-9f * v_abs * r0a) {
        code = 1;
      } else {
        al = rho_l / sigma;
        const double da = (double)al;
        const double ss2 = s[4] - 2.0 * da * s[3] + da * da * s[1];
        const float s_abs = froguard(ss2);
        if (s_abs <= THRC) {
          code = 2; ra = s_abs;
        } else {
          const double tt  = s[5] - 2.0 * da * s[6] + da * da * s[7];
          const double ts  = s[8] - da * s[9] - da * s[10] + da * da * s[11];
          const double sr0 = s[2] - da * s[0];
          const double tr0 = s[12] - da * s[13];
          om = (float)ts / (float)tt;
          const double dw = (double)om;
          const float rho_new = (float)(sr0 - dw * tr0);
          const double rr_new = ss2 - 2.0 * dw * ts + dw * dw * tt;
          be = (al / om) * (rho_new / rho_l);
          ra = froguard(rr_new);
        }
      }
      if (lane == 0) {
        bcf[0] = al; bcf[1] = om; bcf[2] = be; bcf[3] = ra; bci[0] = code;
        if (it == 0) sh_r0abs = r0a;
      }
    } else {
      for (int g = tid - 64; g < 2 * NXI; g += NTHR - 64) {  // v,z,w rows -2,13
        const bool top = g < NXI;
        const int c = top ? g : g - NXI;
        if (top) { if (bs > 0) {
          const size_t nb = (size_t)(bs - 1) * 2 * NXI;
          slabV[c] = aloadf(ghv_sys + nb + NXI + c);
          zbuf[c]  = aloadf(ghz_sys + nb + NXI + c);
          wbuf[c]  = aloadf(ghw_sys + nb + NXI + c);
        }} else { if (bs < BPS - 1) {
          const size_t nb = (size_t)(bs + 1) * 2 * NXI;
          slabV[15 * NXI + c] = aloadf(ghv_sys + nb + c);
          zbuf[3 * NXI + c]   = aloadf(ghz_sys + nb + c);
          wbuf[3 * NXI + c]   = aloadf(ghw_sys + nb + c);
        }}
      }
    }
    __syncthreads();
    const int code = bci[0];

    if (code == 3) continue;          // converged at init: x stays mb; top breaks

    if (code == 1) {
      // ---- restart: p = r = r0 = mb - A x ----
#pragma unroll
      for (int k = 0; k < EPT; k++) {
        const int e = tid + k * NTHR;
        const int lr = e / NXI, c = e - lr * NXI;
        slabV[(lr + 2) * NXI + c] = xreg[k];
        if (lr == 0)  astoref(ghx_own + c, xreg[k]);
        if (lr == 11) astoref(ghx_own + NXI + c, xreg[k]);
      }
      sys_bar(flags, &bphase, tid, bs);  // R1
      for (int g = tid; g < 2 * NXI; g += NTHR) {
        const bool top = g < NXI;
        const int c = top ? g : g - NXI;
        if (top) { if (bs > 0)       slabV[1 * NXI + c]  = aloadf(ghx_sys + (size_t)(bs - 1) * 2 * NXI + NXI + c); }
        else     { if (bs < BPS - 1) slabV[14 * NXI + c] = aloadf(ghx_sys + (size_t)(bs + 1) * 2 * NXI + c); }
      }
      __syncthreads();
      double pp = 0;
#pragma unroll
      for (int k = 0; k < EPT; k++) {
        const int e = tid + k * NTHR;
        const int lr = e / NXI, c = e - lr * NXI;
        const float pn = mb - applyA(slabV, lr, c, gr0 + lr, cbmo, cbom);
        preg[k] = pn; rreg[k] = pn; r0reg[k] = pn;
        slabP[(lr + 2) * NXI + c] = pn;
        slabR[(lr + 2) * NXI + c] = pn;
        if (lr == 0)  astoref(ghq_own + c, pn);
        if (lr == 1)  astoref(ghq_own + NXI + c, pn);
        if (lr == 10) astoref(ghq_own + 2 * NXI + c, pn);
        if (lr == 11) astoref(ghq_own + 3 * NXI + c, pn);
        pp += (double)pn * (double)pn;
      }
      bredN(&pp, 1, slots, 28 + par, sys, bs, tid);
      sys_bar(flags, &bphase, tid, bs);  // R2
      if (tid < 64) {
        double sp[1]; shredN(slots, 28 + par, 1, sys, lane, sp);
        const float ra = froguard(sp[0]);
        if (lane == 0) { bcf[3] = ra; sh_r0abs = ra; }
      } else {
        for (int g = tid - 64; g < 4 * NXI; g += NTHR - 64) {
          const int gi = g / NXI, c = g - gi * NXI;
          const int r = (gi < 2) ? gi - 2 : gi + 10;
          if ((r < 0) ? (bs > 0) : (bs < BPS - 1)) {
            float pn;
            if (gi == 0)      pn = aloadf(ghq_sys + (size_t)(bs - 1) * 4 * NXI + 2 * NXI + c);
            else if (gi == 1) pn = aloadf(ghq_sys + (size_t)(bs - 1) * 4 * NXI + 3 * NXI + c);
            else if (gi == 2) pn = aloadf(ghq_sys + (size_t)(bs + 1) * 4 * NXI + c);
            else              pn = aloadf(ghq_sys + (size_t)(bs + 1) * 4 * NXI + NXI + c);
            slabP[(r + 2) * NXI + c] = pn;
            slabR[(r + 2) * NXI + c] = pn;
          }
        }
      }
      continue;   // loop-top syncthreads publishes bc + slabs
    }

    const float alpha = bcf[0];
    if (code == 2) {
      // C3: x += alpha*p ; r = s (terminal: top breaks next round)
#pragma unroll
      for (int k = 0; k < EPT; k++) {
        xreg[k] = xreg[k] + alpha * preg[k];
        rreg[k] = rreg[k] - alpha * vreg[k];
      }
      continue;
    }

    // ---- main update: t = z - alpha*w; x,r,p own + ghost maintenance ----
    const float omega = bcf[1];
    const float beta  = bcf[2];
    for (int g = tid; g < 2 * NXI; g += NTHR) {      // w ghosts rows -1,12 (local)
      const bool top = g < NXI;
      if (top ? (bs > 0) : (bs < BPS - 1)) {
        const int c = top ? g : g - NXI;
        const int r = top ? -1 : 12;
        wbuf[(top ? 1 : 2) * NXI + c] = applyA(slabV, r, c, gr0 + r, cbmo, cbom);
      }
    }
    __syncthreads();   // wbuf + received ghosts visible
#pragma unroll
    for (int k = 0; k < EPT; k++) {
      const int e = tid + k * NTHR;
      const int lr = e / NXI, c = e - lr * NXI;
      const float sc = rreg[k] - alpha * vreg[k];
      xreg[k] = xreg[k] + alpha * preg[k] + omega * sc;
      const float tn = zreg[k] - alpha * wreg[k];
      const float rn = sc - omega * tn;
      const float pn = rn + beta * (preg[k] - omega * vreg[k]);
      rreg[k] = rn;
      preg[k] = pn;
      slabR[(lr + 2) * NXI + c] = rn;
      slabP[(lr + 2) * NXI + c] = pn;
    }
    for (int g = tid; g < 4 * NXI; g += NTHR) {      // ghost rows -2,-1,12,13
      const int gi = g / NXI, c = g - gi * NXI;
      const int r = (gi < 2) ? gi - 2 : gi + 10;
      if ((r < 0) ? (bs > 0) : (bs < BPS - 1)) {
        const int ci = (r + 2) * NXI + c;
        const float rg = slabR[ci];
        const float vg = slabV[ci];
        const float sg = rg - alpha * vg;
        const float tg = zbuf[gi * NXI + c] - alpha * wbuf[gi * NXI + c];
        const float rgn = sg - omega * tg;
        const float pgn = rgn + beta * (slabP[ci] - omega * vg);
        slabR[ci] = rgn;
        slabP[ci] = pgn;
      }
    }
    // no barrier: next P1 reads only block-local LDS (loop-top syncthreads)
  }

  // final write-out of x
#pragma unroll
  for (int k = 0; k < EPT; k++) {
    xs[tid + k * NTHR] = xreg[k];
  }
}

extern "C" void kernel_launch(void* const* d_in, const int* in_sizes, int n_in,
                              void* d_out, int out_size, void* d_ws, size_t ws_size,
                              hipStream_t stream) {
  const float* V  = (const float*)d_in[0];
  const float* M1 = (const float*)d_in[1];
  const float* M2 = (const float*)d_in[2];
  float* xout = (float*)d_out;
  float* wsf  = (float*)d_ws;
  hipMemsetAsync(d_ws, 0, 4096, stream);
  bicg_kernel<<<dim3(NBLK), dim3(NTHR), 0, stream>>>(V, M1, M2, xout, wsf);
}

// Round 11
// 642.803 us; speedup vs baseline: 1.8593x; 1.1208x over previous
//
#include <hip/hip_runtime.h>

#define NXI 384
#define NG  (NXI*NXI)          // 147456 elements per system
#define NSYS 8
#define BPS 32                 // blocks per system
#define NBLK (NSYS*BPS)        // 256 blocks
#define NTHR 512               // 8 waves/CU
#define ROWS_PB 12             // rows per block
#define EPB (ROWS_PB*NXI)      // 4608 elements per block
#define EPT (EPB/NTHR)         // 9 elements per thread

// thr = EPS*NX*NY = 1e-9*147456
#define THRC 1.47456e-4f

// ---- relaxed agent-scope accessors ----
__device__ __forceinline__ float aloadf(const float* p) {
  return __hip_atomic_load(p, __ATOMIC_RELAXED, __HIP_MEMORY_SCOPE_AGENT);
}
__device__ __forceinline__ void astoref(float* p, float v) {
  __hip_atomic_store(p, v, __ATOMIC_RELAXED, __HIP_MEMORY_SCOPE_AGENT);
}
__device__ __forceinline__ double aloadd(const double* p) {
  return __hip_atomic_load(p, __ATOMIC_RELAXED, __HIP_MEMORY_SCOPE_AGENT);
}
__device__ __forceinline__ void astored(double* p, double v) {
  __hip_atomic_store(p, v, __ATOMIC_RELAXED, __HIP_MEMORY_SCOPE_AGENT);
}

__device__ __forceinline__ double wave_red(double v) {
#pragma unroll
  for (int off = 32; off > 0; off >>= 1) v += __shfl_down(v, off, 64);
  return v;
}

// ---- per-system flag barrier: contention-free, no RMW (validated r7-r10) ----
__device__ __forceinline__ void sys_bar(unsigned* flags, unsigned* phase, int tid, int bs) {
  __atomic_signal_fence(__ATOMIC_SEQ_CST);
  __builtin_amdgcn_s_waitcnt(0);
  __syncthreads();
  const unsigned ph = ++(*phase);
  if (tid == 0) {
    __hip_atomic_store(flags + bs, ph, __ATOMIC_RELAXED, __HIP_MEMORY_SCOPE_AGENT);
  }
  if (tid < 64) {
    while (true) {
      const unsigned f = __hip_atomic_load(flags + (tid & 31), __ATOMIC_RELAXED,
                                           __HIP_MEMORY_SCOPE_AGENT);
      if (__ballot(f >= ph) == ~0ull) break;
      __builtin_amdgcn_s_sleep(1);
    }
  }
  __syncthreads();
  __atomic_signal_fence(__ATOMIC_SEQ_CST);
}

// Block-reduce n<=9 doubles, agent-store to channels [chan0..][sys][bs].
__device__ __forceinline__ void bredN(const double* v, int n,
                                      double* slots, int chan0,
                                      int sys, int bs, int tid) {
  __shared__ double sred[NTHR/64][9];
  const int wid = tid >> 6, lane = tid & 63;
#pragma unroll
  for (int q = 0; q < n; q++) {
    const double w = wave_red(v[q]);
    if (lane == 0) sred[wid][q] = w;
  }
  __syncthreads();
  if (tid == 0) {
#pragma unroll
    for (int q = 0; q < n; q++) {
      double a = 0.0;
#pragma unroll
      for (int w2 = 0; w2 < NTHR/64; w2++) a += sred[w2][q];
      astored(slots + (size_t)(chan0 + q) * NBLK + sys * BPS + bs, a);
    }
  }
  __syncthreads();
}

// Butterfly sums of n channels (bit-exact identical in every lane/block).
__device__ __forceinline__ void shredN(const double* slots, int chan0, int n,
                                       int sys, int lane, double* out) {
  double v[14];
#pragma unroll
  for (int q = 0; q < n; q++)
    v[q] = aloadd(slots + (size_t)(chan0 + q) * NBLK + sys * BPS + (lane & 31));
#pragma unroll
  for (int q = 0; q < n; q++) {
    double x = v[q];
    x += __shfl_xor(x, 1, 64);
    x += __shfl_xor(x, 2, 64);
    x += __shfl_xor(x, 4, 64);
    x += __shfl_xor(x, 8, 64);
    x += __shfl_xor(x, 16, 64);
    out[q] = x;
  }
}

__device__ __forceinline__ float froguard(double sq) {
  return sq > 0.0 ? (float)sqrt(sq) : 0.0f;
}

// ---- coefficient builders (bit-exact shared op sequences, validated r9/r10) ----
__device__ __forceinline__ float calc_d1b(const float* Vb, const float* M1b, int i, int j) {
  const int a0 = (i - 1 < 0) ? 0 : i - 1;
  const float vc = Vb[j * NXI + i] + 1.0f;
  const float vu = Vb[j * NXI + a0] + 1.0f;
  return M1b[j * NXI + a0] * ((vc - vu) / (0.5f * (vc + vu)));
}
__device__ __forceinline__ float calc_d2b(const float* Vb, const float* M2b, int i, int j) {
  const int b0 = (j - 1 < 0) ? 0 : j - 1;
  const float vc = Vb[j * NXI + i] + 1.0f;
  const float vl = Vb[b0 * NXI + i] + 1.0f;
  return M2b[b0 * NXI + i] * ((vc - vl) / (0.5f * (vc + vl)));
}

// 5-point stencil. Coeffs: bmo rows -1..13, bom rows -1..12 at (r+1)*NXI.
// bpo(i,j)=-20-bmo(i+1,j) (-10 at i=383); bop(i,j)=-20-bom(i,j+1) (-10 at j=383);
// boo = 81 + bmo + bom + bpo + bop (exact identities). src rows -2..13 at (r+2)*NXI.
__device__ __forceinline__ float applyA(const float* src, int r, int c, int gr,
                                        const float* cbmo, const float* cbom) {
  const int ci = (r + 1) * NXI + c;
  const int si = (r + 2) * NXI + c;
  const float uc = src[si];
  const float um = (gr == 0)       ? uc : src[si - NXI];
  const float ud = (gr == NXI - 1) ? uc : src[si + NXI];
  const float ul = (c == 0)        ? uc : src[si - 1];
  const float ur = (c == NXI - 1)  ? uc : src[si + 1];
  const float bmo = cbmo[ci], bom = cbom[ci];
  const float bpo = (gr < NXI - 1) ? (-20.0f - cbmo[ci + NXI]) : -10.0f;
  const float bop = (c < NXI - 1)  ? (-20.0f - cbom[ci + 1])   : -10.0f;
  const float boo = 81.0f + bmo + bom + bpo + bop;
  return boo * uc + bmo * um + bom * ul + bop * ur + bpo * ud;
}

// rowsum from stored coeffs (rows -1..12)
__device__ __forceinline__ float coeff_sum_stored(int r, int c, int gr,
                                                  const float* cbmo, const float* cbom) {
  const int ci = (r + 1) * NXI + c;
  const float bmo = cbmo[ci], bom = cbom[ci];
  const float bpo = (gr < NXI - 1) ? (-20.0f - cbmo[ci + NXI]) : -10.0f;
  const float bop = (c < NXI - 1)  ? (-20.0f - cbom[ci + 1])   : -10.0f;
  const float boo = 81.0f + bmo + bom + bpo + bop;
  return boo + bmo + bom + bpo + bop;
}
// same rowsum mirrored op-for-op from V/M (rows -2,13; validated r9/r10)
__device__ __forceinline__ float coeff_sum_direct(const float* Vb, const float* M1b,
                                                  const float* M2b, int gr, int c) {
  const float bmo = -10.0f - 5.0f * calc_d1b(Vb, M1b, gr, c);
  const float bom = -10.0f - 5.0f * calc_d2b(Vb, M2b, gr, c);
  float bpo;
  if (gr < NXI - 1) {
    const float bmon = -10.0f - 5.0f * calc_d1b(Vb, M1b, gr + 1, c);
    bpo = -20.0f - bmon;
  } else bpo = -10.0f;
  float bop;
  if (c < NXI - 1) {
    const float bomn = -10.0f - 5.0f * calc_d2b(Vb, M2b, gr, c + 1);
    bop = -20.0f - bomn;
  } else bop = -10.0f;
  const float boo = 81.0f + bmo + bom + bpo + bop;
  return boo + bmo + bom + bpo + bop;
}

__global__ __launch_bounds__(NTHR, 2) void bicg_kernel(
    const float* __restrict__ V, const float* __restrict__ M1, const float* __restrict__ M2,
    float* __restrict__ xout, float* __restrict__ wsf) {
  const int blk = blockIdx.x;
  const int sys = blk & (NSYS - 1);
  const int bs  = blk >> 3;
  const int tid = threadIdx.x;
  const int lane = tid & 63;
  const int gr0 = bs * ROWS_PB;

  // ---- LDS (~112 KB) ----
  __shared__ float slabP[16 * NXI];     // p rows -2..13
  __shared__ float slabV[16 * NXI];     // v rows -2..13 (x staging in restart)
  __shared__ float cbmo[15 * NXI];      // rows -1..13
  __shared__ float cbom[14 * NXI];      // rows -1..12
  __shared__ float rgh[4 * NXI];        // r ghosts rows -2,-1,12,13 (recursive)
  __shared__ float wgh[4 * NXI];        // w ghosts (refreshed every iter)
  __shared__ float ugh[4 * NXI];        // u = beta*(v - omega*w) ghosts (recursive)
  __shared__ float bcf[4];              // 0:alpha 1:omega 2:beta 3:r_abs
  __shared__ int   bci[1];              // 0 normal, 1 RES, 2 C3, 3 SKIP
  __shared__ float sh_r0abs;

  // ---- workspace ----
  unsigned* flags = (unsigned*)wsf + sys * 32;
  double* slots = (double*)(wsf + 1024);                // 32 chans * 256 doubles
  const size_t PSZ = (size_t)NSYS * BPS * 2 * NXI;
  float* gbase = wsf + 32768;
  float* ghv = gbase;                                    // [2(par)][sys][bs][2][NXI]
  float* ghw = ghv + 2 * PSZ;
  float* ghx = ghw + 2 * PSZ;                            // restart x halos [sys][bs][2][NXI]
  float* ghq = ghx + PSZ;                                // restart p halos [sys][bs][4][NXI]
  float* ghx_sys = ghx + (size_t)sys * BPS * 2 * NXI;
  float* ghq_sys = ghq + (size_t)sys * BPS * 4 * NXI;
  float* ghx_own = ghx_sys + (size_t)bs * 2 * NXI;
  float* ghq_own = ghq_sys + (size_t)bs * 4 * NXI;

  unsigned bphase = 0;

  const size_t so = (size_t)sys * NG;
  const float* Vb  = V  + so;
  const float* M1b = M1 + so;
  const float* M2b = M2 + so;
  float* xs = xout + so + (size_t)bs * EPB;

  // ---------- Phase 0: coefficients + V-mean partial ----------
  for (int q = tid; q < 15 * NXI; q += NTHR) {
    const int r = q / NXI - 1;                 // -1..13
    const int gr = gr0 + r;
    if ((unsigned)gr >= (unsigned)NXI) continue;
    const int c = q - (r + 1) * NXI;
    cbmo[q] = -10.0f - 5.0f * calc_d1b(Vb, M1b, gr, c);
    if (r <= 12) cbom[q] = -10.0f - 5.0f * calc_d2b(Vb, M2b, gr, c);
  }
  {
    double vsum = 0.0;
#pragma unroll
    for (int k = 0; k < EPT; k++) vsum += (double)Vb[bs * EPB + tid + k * NTHR];
    bredN(&vsum, 1, slots, 31, sys, bs, tid);
  }
  sys_bar(flags, &bphase, tid, bs);  // S0

  // ---------- Init: x=mb; p=r=r0 = mb - rowsum*mb; u = 0 ----------
  double smb[1]; shredN(slots, 31, 1, sys, lane, smb);
  const float mb = (float)(smb[0] / (double)NG) + 1.0f;
  float preg[EPT], rreg[EPT], r0reg[EPT], vreg[EPT], wreg[EPT], zreg[EPT], ureg[EPT], xreg[EPT];
#pragma unroll
  for (int k = 0; k < EPT; k++) {
    const int e = tid + k * NTHR;
    const int lr = e / NXI, c = e - lr * NXI;
    const float pn = mb - coeff_sum_stored(lr, c, gr0 + lr, cbmo, cbom) * mb;
    xreg[k] = mb;
    preg[k] = pn; rreg[k] = pn; r0reg[k] = pn;
    ureg[k] = 0.0f;
    slabP[(lr + 2) * NXI + c] = pn;
  }
  for (int g = tid; g < 4 * NXI; g += NTHR) {
    const int gi = g / NXI, c = g - gi * NXI;
    const int r = (gi < 2) ? gi - 2 : gi + 10;      // -2,-1,12,13
    ugh[g] = 0.0f;
    if ((r < 0) ? (bs > 0) : (bs < BPS - 1)) {
      const int gr = gr0 + r;
      const float rs = (r == -2 || r == 13)
          ? coeff_sum_direct(Vb, M1b, M2b, gr, c)
          : coeff_sum_stored(r, c, gr, cbmo, cbom);
      const float pn = mb - rs * mb;
      slabP[(r + 2) * NXI + c] = pn;
      rgh[g] = pn;
    }
  }
  if (tid == 0) { bcf[3] = 1.0f; bci[0] = 0; }

  for (int it = 0; it < 30; ++it) {
    __syncthreads();                 // bc + slab writes visible
    if (!(bcf[3] > THRC)) break;     // uniform (LDS broadcast)
    const int par = it & 1;
    float* ghv_sys = ghv + (size_t)par * PSZ + (size_t)sys * BPS * 2 * NXI;
    float* ghw_sys = ghw + (size_t)par * PSZ + (size_t)sys * BPS * 2 * NXI;
    float* ghv_own = ghv_sys + (size_t)bs * 2 * NXI;  // [0]=row1, [NXI]=row10
    float* ghw_own = ghw_sys + (size_t)bs * 2 * NXI;
    const int ch0 = par * 14;

    // ==== pass A: v = A p (own + ghost -1,12); z = v - u; 5 dots ====
    {
      double d[5] = {0, 0, 0, 0, 0};
#pragma unroll
      for (int k = 0; k < EPT; k++) {
        const int e = tid + k * NTHR;
        const int lr = e / NXI, c = e - lr * NXI;
        const float vv = applyA(slabP, lr, c, gr0 + lr, cbmo, cbom);
        vreg[k] = vv;
        zreg[k] = vv - ureg[k];             // z = A r by linearity recursion
        slabV[(lr + 2) * NXI + c] = vv;
        if (lr == 1)  astoref(ghv_own + c, vv);
        if (lr == 10) astoref(ghv_own + NXI + c, vv);
        d[0] += (double)vv * (double)r0reg[k];
        d[1] += (double)vv * (double)vv;
        d[2] += (double)rreg[k] * (double)r0reg[k];
        d[3] += (double)rreg[k] * (double)vv;
        d[4] += (double)rreg[k] * (double)rreg[k];
      }
      for (int g = tid; g < 2 * NXI; g += NTHR) {      // v ghosts rows -1,12
        const bool top = g < NXI;
        if (top ? (bs > 0) : (bs < BPS - 1)) {
          const int c = top ? g : g - NXI;
          const int r = top ? -1 : 12;
          slabV[(r + 2) * NXI + c] = applyA(slabP, r, c, gr0 + r, cbmo, cbom);
        }
      }
      bredN(d, 5, slots, ch0, sys, bs, tid);   // internal syncs publish slabV
    }
    // ==== pass B: w = A v (own); 9 dots ====
    {
      double d[9] = {0, 0, 0, 0, 0, 0, 0, 0, 0};
#pragma unroll
      for (int k = 0; k < EPT; k++) {
        const int e = tid + k * NTHR;
        const int lr = e / NXI, c = e - lr * NXI;
        const float ww = applyA(slabV, lr, c, gr0 + lr, cbmo, cbom);
        wreg[k] = ww;
        if (lr == 1)  astoref(ghw_own + c, ww);
        if (lr == 10) astoref(ghw_own + NXI + c, ww);
        const float zz = zreg[k];
        d[0] += (double)zz * (double)zz;
        d[1] += (double)zz * (double)ww;
        d[2] += (double)ww * (double)ww;
        d[3] += (double)zz * (double)rreg[k];
        d[4] += (double)zz * (double)vreg[k];
        d[5] += (double)ww * (double)rreg[k];
        d[6] += (double)ww * (double)vreg[k];
        d[7] += (double)zz * (double)r0reg[k];
        d[8] += (double)ww * (double)r0reg[k];
      }
      bredN(d, 9, slots, ch0 + 5, sys, bs, tid);
    }
    sys_bar(flags, &bphase, tid, bs);  // THE barrier

    // ==== post-barrier: wave0 scalars; waves 1-7 receive v,w rows -2,13 ====
    if (tid < 64) {
      double s[14];
      shredN(slots, ch0, 14, sys, lane, s);
      const float sigma = (float)s[0];
      const float v_abs = froguard(s[1]);
      const float rho_l = (float)s[2];
      const float r0a = (it == 0) ? froguard(s[4]) : sh_r0abs;
      int code = 0;
      float al = 0.f, om = 0.f, be = 0.f, ra = 0.f;
      if (it == 0 && !(r0a > THRC)) {
        code = 3; ra = r0a;
      } else if (sigma <= 1e-9f * v_abs * r0a) {
        code = 1;
      } else {
        al = rho_l / sigma;
        const double da = (double)al;
        const double ss2 = s[4] - 2.0 * da * s[3] + da * da * s[1];
        const float s_abs = froguard(ss2);
        if (s_abs <= THRC) {
          code = 2; ra = s_abs;
        } else {
          const double tt  = s[5] - 2.0 * da * s[6] + da * da * s[7];
          const double ts  = s[8] - da * s[9] - da * s[10] + da * da * s[11];
          const double sr0 = s[2] - da * s[0];
          const double tr0 = s[12] - da * s[13];
          om = (float)ts / (float)tt;
          const double dw = (double)om;
          const float rho_new = (float)(sr0 - dw * tr0);
          const double rr_new = ss2 - 2.0 * dw * ts + dw * dw * tt;
          be = (al / om) * (rho_new / rho_l);
          ra = froguard(rr_new);
        }
      }
      if (lane == 0) {
        bcf[0] = al; bcf[1] = om; bcf[2] = be; bcf[3] = ra; bci[0] = code;
        if (it == 0) sh_r0abs = r0a;
      }
    } else {
      for (int g = tid - 64; g < 2 * NXI; g += NTHR - 64) {  // v,w rows -2,13
        const bool top = g < NXI;
        const int c = top ? g : g - NXI;
        if (top) { if (bs > 0) {
          const size_t nb = (size_t)(bs - 1) * 2 * NXI;
          slabV[c] = aloadf(ghv_sys + nb + NXI + c);
          wgh[c]   = aloadf(ghw_sys + nb + NXI + c);
        }} else { if (bs < BPS - 1) {
          const size_t nb = (size_t)(bs + 1) * 2 * NXI;
          slabV[15 * NXI + c] = aloadf(ghv_sys + nb + c);
          wgh[3 * NXI + c]    = aloadf(ghw_sys + nb + c);
        }}
      }
    }
    __syncthreads();
    const int code = bci[0];

    if (code == 3) continue;          // converged at init: x stays mb; top breaks

    if (code == 1) {
      // ---- restart: p = r = r0 = mb - A x ; u = 0 ----
#pragma unroll
      for (int k = 0; k < EPT; k++) {
        const int e = tid + k * NTHR;
        const int lr = e / NXI, c = e - lr * NXI;
        slabV[(lr + 2) * NXI + c] = xreg[k];
        if (lr == 0)  astoref(ghx_own + c, xreg[k]);
        if (lr == 11) astoref(ghx_own + NXI + c, xreg[k]);
      }
      sys_bar(flags, &bphase, tid, bs);  // R1
      for (int g = tid; g < 2 * NXI; g += NTHR) {
        const bool top = g < NXI;
        const int c = top ? g : g - NXI;
        if (top) { if (bs > 0)       slabV[1 * NXI + c]  = aloadf(ghx_sys + (size_t)(bs - 1) * 2 * NXI + NXI + c); }
        else     { if (bs < BPS - 1) slabV[14 * NXI + c] = aloadf(ghx_sys + (size_t)(bs + 1) * 2 * NXI + c); }
      }
      __syncthreads();
      double pp = 0;
#pragma unroll
      for (int k = 0; k < EPT; k++) {
        const int e = tid + k * NTHR;
        const int lr = e / NXI, c = e - lr * NXI;
        const float pn = mb - applyA(slabV, lr, c, gr0 + lr, cbmo, cbom);
        preg[k] = pn; rreg[k] = pn; r0reg[k] = pn;
        ureg[k] = 0.0f;
        slabP[(lr + 2) * NXI + c] = pn;
        if (lr == 0)  astoref(ghq_own + c, pn);
        if (lr == 1)  astoref(ghq_own + NXI + c, pn);
        if (lr == 10) astoref(ghq_own + 2 * NXI + c, pn);
        if (lr == 11) astoref(ghq_own + 3 * NXI + c, pn);
        pp += (double)pn * (double)pn;
      }
      bredN(&pp, 1, slots, 28 + par, sys, bs, tid);
      sys_bar(flags, &bphase, tid, bs);  // R2
      if (tid < 64) {
        double sp[1]; shredN(slots, 28 + par, 1, sys, lane, sp);
        const float ra = froguard(sp[0]);
        if (lane == 0) { bcf[3] = ra; sh_r0abs = ra; }
      } else {
        for (int g = tid - 64; g < 4 * NXI; g += NTHR - 64) {
          const int gi = g / NXI, c = g - gi * NXI;
          const int r = (gi < 2) ? gi - 2 : gi + 10;
          ugh[g] = 0.0f;
          if ((r < 0) ? (bs > 0) : (bs < BPS - 1)) {
            float pn;
            if (gi == 0)      pn = aloadf(ghq_sys + (size_t)(bs - 1) * 4 * NXI + 2 * NXI + c);
            else if (gi == 1) pn = aloadf(ghq_sys + (size_t)(bs - 1) * 4 * NXI + 3 * NXI + c);
            else if (gi == 2) pn = aloadf(ghq_sys + (size_t)(bs + 1) * 4 * NXI + c);
            else              pn = aloadf(ghq_sys + (size_t)(bs + 1) * 4 * NXI + NXI + c);
            slabP[(r + 2) * NXI + c] = pn;
            rgh[g] = pn;
          }
        }
      }
      continue;   // loop-top syncthreads publishes bc + slabs
    }

    const float alpha = bcf[0];
    if (code == 2) {
      // C3: x += alpha*p ; r = s (terminal: top breaks next round)
#pragma unroll
      for (int k = 0; k < EPT; k++) {
        xreg[k] = xreg[k] + alpha * preg[k];
        rreg[k] = rreg[k] - alpha * vreg[k];
      }
      continue;
    }

    // ---- main update: t = z - alpha*w; x,r,p,u own + ghost maintenance ----
    const float omega = bcf[1];
    const float beta  = bcf[2];
    for (int g = tid; g < 2 * NXI; g += NTHR) {      // w ghosts rows -1,12 (local)
      const bool top = g < NXI;
      if (top ? (bs > 0) : (bs < BPS - 1)) {
        const int c = top ? g : g - NXI;
        const int r = top ? -1 : 12;
        wgh[(top ? 1 : 2) * NXI + c] = applyA(slabV, r, c, gr0 + r, cbmo, cbom);
      }
    }
    __syncthreads();   // wgh + received ghosts visible
#pragma unroll
    for (int k = 0; k < EPT; k++) {
      const int e = tid + k * NTHR;
      const int lr = e / NXI, c = e - lr * NXI;
      const float sc = rreg[k] - alpha * vreg[k];
      xreg[k] = xreg[k] + alpha * preg[k] + omega * sc;
      const float tn = zreg[k] - alpha * wreg[k];
      const float rn = sc - omega * tn;
      const float pn = rn + beta * (preg[k] - omega * vreg[k]);
      rreg[k] = rn;
      preg[k] = pn;
      ureg[k] = beta * (vreg[k] - omega * wreg[k]);   // u for next iter's z
      slabP[(lr + 2) * NXI + c] = pn;
    }
    for (int g = tid; g < 4 * NXI; g += NTHR) {      // ghost rows -2,-1,12,13
      const int gi = g / NXI, c = g - gi * NXI;
      const int r = (gi < 2) ? gi - 2 : gi + 10;
      if ((r < 0) ? (bs > 0) : (bs < BPS - 1)) {
        const int ci = (r + 2) * NXI + c;
        const float vg = slabV[ci];
        const float wg = wgh[g];
        const float zg = vg - ugh[g];
        const float rg = rgh[g];
        const float sg = rg - alpha * vg;
        const float tg = zg - alpha * wg;
        const float rgn = sg - omega * tg;
        const float pgn = rgn + beta * (slabP[ci] - omega * vg);
        rgh[g] = rgn;
        ugh[g] = beta * (vg - omega * wg);
        slabP[ci] = pgn;
      }
    }
    // no barrier: next pass A reads only block-local LDS (loop-top syncthreads)
  }

  // final write-out of x
#pragma unroll
  for (int k = 0; k < EPT; k++) {
    xs[tid + k * NTHR] = xreg[k];
  }
}

extern "C" void kernel_launch(void* const* d_in, const int* in_sizes, int n_in,
                              void* d_out, int out_size, void* d_ws, size_t ws_size,
                              hipStream_t stream) {
  const float* V  = (const float*)d_in[0];
  const float* M1 = (const float*)d_in[1];
  const float* M2 = (const float*)d_in[2];
  float* xout = (float*)d_out;
  float* wsf  = (float*)d_ws;
  hipMemsetAsync(d_ws, 0, 4096, stream);
  bicg_kernel<<<dim3(NBLK), dim3(NTHR), 0, stream>>>(V, M1, M2, xout, wsf);
}

// Round 12
// 529.157 us; speedup vs baseline: 2.2586x; 1.2148x over previous
//
#include <hip/hip_runtime.h>

#define NXI 384
#define NG  (NXI*NXI)          // 147456 elements per system
#define NSYS 8
#define BPS 32                 // blocks per system
#define NBLK (NSYS*BPS)        // 256 blocks
#define NTHR 512               // 8 waves/CU
#define ROWS_PB 12             // rows per block
#define EPB (ROWS_PB*NXI)      // 4608 elements per block
#define EPT (EPB/NTHR)         // 9 elements per thread

// thr = EPS*NX*NY = 1e-9*147456
#define THRC 1.47456e-4f

// ---- relaxed agent-scope accessors ----
__device__ __forceinline__ float aloadf(const float* p) {
  return __hip_atomic_load(p, __ATOMIC_RELAXED, __HIP_MEMORY_SCOPE_AGENT);
}
__device__ __forceinline__ void astoref(float* p, float v) {
  __hip_atomic_store(p, v, __ATOMIC_RELAXED, __HIP_MEMORY_SCOPE_AGENT);
}
__device__ __forceinline__ double aloadd(const double* p) {
  return __hip_atomic_load(p, __ATOMIC_RELAXED, __HIP_MEMORY_SCOPE_AGENT);
}
__device__ __forceinline__ void astored(double* p, double v) {
  __hip_atomic_store(p, v, __ATOMIC_RELAXED, __HIP_MEMORY_SCOPE_AGENT);
}

__device__ __forceinline__ double wave_red(double v) {
#pragma unroll
  for (int off = 32; off > 0; off >>= 1) v += __shfl_down(v, off, 64);
  return v;
}

// ---- per-system flag barrier: contention-free, no RMW (validated r7-r11) ----
__device__ __forceinline__ void sys_bar(unsigned* flags, unsigned* phase, int tid, int bs) {
  __atomic_signal_fence(__ATOMIC_SEQ_CST);
  __builtin_amdgcn_s_waitcnt(0);
  __syncthreads();
  const unsigned ph = ++(*phase);
  if (tid == 0) {
    __hip_atomic_store(flags + bs, ph, __ATOMIC_RELAXED, __HIP_MEMORY_SCOPE_AGENT);
  }
  if (tid < 64) {
    while (true) {
      const unsigned f = __hip_atomic_load(flags + (tid & 31), __ATOMIC_RELAXED,
                                           __HIP_MEMORY_SCOPE_AGENT);
      if (__ballot(f >= ph) == ~0ull) break;
      __builtin_amdgcn_s_sleep(1);
    }
  }
  __syncthreads();
  __atomic_signal_fence(__ATOMIC_SEQ_CST);
}

// Block-reduce n<=5 doubles, agent-store to channels [chan0..][sys][bs].
__device__ __forceinline__ void bredN(const double* v, int n,
                                      double* slots, int chan0,
                                      int sys, int bs, int tid) {
  __shared__ double sred[NTHR/64][5];
  const int wid = tid >> 6, lane = tid & 63;
#pragma unroll
  for (int q = 0; q < n; q++) {
    const double w = wave_red(v[q]);
    if (lane == 0) sred[wid][q] = w;
  }
  __syncthreads();
  if (tid == 0) {
#pragma unroll
    for (int q = 0; q < n; q++) {
      double a = 0.0;
#pragma unroll
      for (int w2 = 0; w2 < NTHR/64; w2++) a += sred[w2][q];
      astored(slots + (size_t)(chan0 + q) * NBLK + sys * BPS + bs, a);
    }
  }
  __syncthreads();
}

// Butterfly sums of n channels (bit-exact identical in every lane/block).
__device__ __forceinline__ void shredN(const double* slots, int chan0, int n,
                                       int sys, int lane, double* out) {
  double v[5];
#pragma unroll
  for (int q = 0; q < n; q++)
    v[q] = aloadd(slots + (size_t)(chan0 + q) * NBLK + sys * BPS + (lane & 31));
#pragma unroll
  for (int q = 0; q < n; q++) {
    double x = v[q];
    x += __shfl_xor(x, 1, 64);
    x += __shfl_xor(x, 2, 64);
    x += __shfl_xor(x, 4, 64);
    x += __shfl_xor(x, 8, 64);
    x += __shfl_xor(x, 16, 64);
    out[q] = x;
  }
}

__device__ __forceinline__ float froguard(double sq) {
  return sq > 0.0 ? (float)sqrt(sq) : 0.0f;
}

__global__ __launch_bounds__(NTHR, 1) void bicg_kernel(
    const float* __restrict__ V, const float* __restrict__ M1, const float* __restrict__ M2,
    float* __restrict__ xout, float* __restrict__ wsf) {
  const int blk = blockIdx.x;
  const int sys = blk & (NSYS - 1);
  const int bs  = blk >> 3;
  const int tid = threadIdx.x;
  const int lane = tid & 63;
  const int gr0 = bs * ROWS_PB;

  // ---- LDS (~160 KB): rows -1..12 -> index (r+1)*NXI ----
  __shared__ float slabP[14 * NXI];   // p (own + 1 ghost row/side)
  __shared__ float slabS[14 * NXI];   // s (own + ghost); x staging during restart
  __shared__ float cf[5][14 * NXI];   // coeffs rows -1..12
  __shared__ float vgh[2 * NXI];      // received v ghosts: [0..NXI)=row -1, rest=row 12
  __shared__ float tgh[2 * NXI];      // received t ghosts
  __shared__ float rgh[2 * NXI];      // maintained r ghosts (recursive, bit-exact)
  __shared__ float bcf[4];            // 0:alpha 1:omega 2:beta 3:r_abs
  __shared__ int   bci[1];            // 0 normal, 1 RES, 2 C3, 3 converged-at-init
  __shared__ float sh_r0abs, sh_rho;
  __shared__ double sh_ss2;
  float* cboo = cf[0]; float* cbmo = cf[1]; float* cbom = cf[2];
  float* cbop = cf[3]; float* cbpo = cf[4];

  // ---- workspace (control + boundary rows only) ----
  unsigned* flags = (unsigned*)wsf + sys * 32;      // memset 0 before launch
  double* slots = (double*)(wsf + 1024);            // 11 chans * 256 doubles
  float* ghv_all = wsf + 16384;                     // [sys][bs][2][NXI] v boundary
  float* ght_all = ghv_all + (size_t)NSYS * BPS * 2 * NXI;  // t boundary
  float* ghx_all = ght_all + (size_t)NSYS * BPS * 2 * NXI;  // x boundary (restart)
  float* ghq_all = ghx_all + (size_t)NSYS * BPS * 2 * NXI;  // p boundary (restart)
  float* ghv = ghv_all + (size_t)sys * BPS * 2 * NXI;
  float* ght = ght_all + (size_t)sys * BPS * 2 * NXI;
  float* ghx = ghx_all + (size_t)sys * BPS * 2 * NXI;
  float* ghq = ghq_all + (size_t)sys * BPS * 2 * NXI;
  float* ghv_own = ghv + (size_t)bs * 2 * NXI;      // [0]=row0, [NXI]=row11
  float* ght_own = ght + (size_t)bs * 2 * NXI;
  float* ghx_own = ghx + (size_t)bs * 2 * NXI;
  float* ghq_own = ghq + (size_t)bs * 2 * NXI;

  unsigned bphase = 0;

  const size_t so = (size_t)sys * NG;
  const float* Vb  = V  + so;
  const float* M1b = M1 + so;
  const float* M2b = M2 + so;
  float* xs = xout + so + (size_t)bs * EPB;

  // ---------- Phase 0: coeffs rows -1..12 (LDS) + V-mean partial ----------
  for (int q = tid; q < 14 * NXI; q += NTHR) {
    const int lr2 = q / NXI - 1;
    const int gr = gr0 + lr2;
    if ((unsigned)gr >= (unsigned)NXI) continue;
    const int j = q - (lr2 + 1) * NXI;
    const int i = gr;
    const int a0 = (i - 1 < 0) ? 0 : i - 1;
    const int a1 = i;
    const int a2 = (i + 1 > NXI - 1) ? NXI - 1 : i + 1;
    const int b0 = (j - 1 < 0) ? 0 : j - 1;
    const int b1 = j;
    const int b2 = (j + 1 > NXI - 1) ? NXI - 1 : j + 1;
    const float vc = Vb[b1 * NXI + a1] + 1.0f;
    const float vu = Vb[b1 * NXI + a0] + 1.0f;
    const float vd = Vb[b1 * NXI + a2] + 1.0f;
    const float vl = Vb[b0 * NXI + a1] + 1.0f;
    const float vr = Vb[b2 * NXI + a1] + 1.0f;
    const float D1A = M1b[b1 * NXI + a1] * ((vd - vc) / (0.5f * (vd + vc)));
    const float D1B = M1b[b1 * NXI + a0] * ((vc - vu) / (0.5f * (vc + vu)));
    const float D2A = M2b[b1 * NXI + a1] * ((vr - vc) / (0.5f * (vr + vc)));
    const float D2B = M2b[b0 * NXI + a1] * ((vc - vl) / (0.5f * (vc + vl)));
    cboo[q] = 41.0f - 5.0f * (D1B - D1A) - 5.0f * (D2B - D2A);
    cbpo[q] = -10.0f + 5.0f * D1A;
    cbmo[q] = -10.0f - 5.0f * D1B;
    cbop[q] = -10.0f + 5.0f * D2A;
    cbom[q] = -10.0f - 5.0f * D2B;
  }
  {
    double vsum = 0.0;
#pragma unroll
    for (int k = 0; k < EPT; k++) vsum += (double)Vb[bs * EPB + tid + k * NTHR];
    bredN(&vsum, 1, slots, 9, sys, bs, tid);
  }
  sys_bar(flags, &bphase, tid, bs);  // S0 (only setup barrier)

  // ---------- Init: x=mb; p=r=r0 = mb - rowsum*mb on own AND ghost rows ----------
  double smb[1]; shredN(slots, 9, 1, sys, lane, smb);
  const float mb = (float)(smb[0] / (double)NG) + 1.0f;
  float preg[EPT], rreg[EPT], r0reg[EPT], vreg[EPT], treg[EPT], xreg[EPT];
#pragma unroll
  for (int k = 0; k < EPT; k++) {
    const int e = tid + k * NTHR;
    const int ce = e + NXI;
    const float ax = (cboo[ce] + cbmo[ce] + cbom[ce] + cbop[ce] + cbpo[ce]) * mb;
    const float pn = mb - ax;
    xreg[k] = mb;
    preg[k] = pn; rreg[k] = pn; r0reg[k] = pn;
    slabP[ce] = pn;
  }
  for (int g = tid; g < 2 * NXI; g += NTHR) {
    const bool top = g < NXI;
    if (top ? (bs > 0) : (bs < BPS - 1)) {
      const int c = top ? g : g - NXI;
      const int ci = top ? c : 13 * NXI + c;     // row -1 / row 12 index
      const float pn = mb - (cboo[ci] + cbmo[ci] + cbom[ci] + cbop[ci] + cbpo[ci]) * mb;
      slabP[ci] = pn;
      rgh[g] = pn;
    }
  }
  if (tid == 0) { bcf[3] = 1.0f; bci[0] = 0; }

  for (int it = 0; it < 30; ++it) {
    __syncthreads();                 // bcf/slab writes visible
    if (!(bcf[3] > THRC)) break;     // uniform within system

    // ==== P1: v = A p own rows; publish v rows 0/11; 5 dots ====
    {
      double d[5] = {0, 0, 0, 0, 0};
#pragma unroll
      for (int k = 0; k < EPT; k++) {
        const int e = tid + k * NTHR;
        const int lr = e / NXI, c = e - lr * NXI;
        const int gr = gr0 + lr;
        const int ce = e + NXI;
        const float uc = preg[k];
        const float um = (gr == 0)       ? uc : slabP[ce - NXI];
        const float ud = (gr == NXI - 1) ? uc : slabP[ce + NXI];
        const float ul = (c == 0)        ? uc : slabP[ce - 1];
        const float ur = (c == NXI - 1)  ? uc : slabP[ce + 1];
        const float vv = cboo[ce] * uc + cbmo[ce] * um + cbom[ce] * ul + cbop[ce] * ur + cbpo[ce] * ud;
        vreg[k] = vv;
        if (lr == 0)  astoref(ghv_own + c, vv);
        if (lr == 11) astoref(ghv_own + NXI + c, vv);
        d[0] += (double)vv * (double)r0reg[k];      // sigma
        d[1] += (double)vv * (double)vv;            // <v,v>
        d[2] += (double)rreg[k] * (double)r0reg[k]; // rho
        d[3] += (double)rreg[k] * (double)vv;       // <r,v>
        d[4] += (double)rreg[k] * (double)rreg[k];  // <r,r>
      }
      bredN(d, 5, slots, 0, sys, bs, tid);
    }
    sys_bar(flags, &bphase, tid, bs);  // B

    // ==== P2: wave0 scalars || waves1-7 receive v ghosts; then branch ====
    if (tid < 64) {
      double s[5];
      shredN(slots, 0, 5, sys, lane, s);
      const float sigma = (float)s[0];
      const float v_abs = froguard(s[1]);
      const float rho_l = (float)s[2];
      const float r0a = (it == 0) ? froguard(s[4]) : sh_r0abs;
      int code = 0;
      float al = 0.f, ra = 0.f;
      double ss2 = 0.0;
      if (it == 0 && !(r0a > THRC)) {
        code = 3; ra = r0a;
      } else if (sigma <= 1e-9f * v_abs * r0a) {
        code = 1;
      } else {
        al = rho_l / sigma;
        const double da = (double)al;
        ss2 = s[4] - 2.0 * da * s[3] + da * da * s[1];   // <s,s> analytic
        const float s_abs = froguard(ss2);
        if (s_abs <= THRC) { code = 2; ra = s_abs; }
      }
      if (lane == 0) {
        bci[0] = code; bcf[0] = al;
        if (code == 2 || code == 3) bcf[3] = ra;
        sh_ss2 = ss2; sh_rho = rho_l;
        if (it == 0) sh_r0abs = r0a;
      }
    } else {
      for (int g = tid - 64; g < 2 * NXI; g += NTHR - 64) {
        const bool top = g < NXI;
        const int c = top ? g : g - NXI;
        if (top) { if (bs > 0)       vgh[g] = aloadf(ghv + (size_t)(bs - 1) * 2 * NXI + NXI + c); }
        else     { if (bs < BPS - 1) vgh[g] = aloadf(ghv + (size_t)(bs + 1) * 2 * NXI + c); }
      }
    }
    __syncthreads();
    const int code = bci[0];

    if (code == 3) continue;          // converged at init: x stays mb; top breaks

    if (code == 1) {
      // ---- restart: p = r = r0 = mb - A x (explicit 1-row exchanges) ----
#pragma unroll
      for (int k = 0; k < EPT; k++) {
        const int e = tid + k * NTHR;
        const int lr = e / NXI, c = e - lr * NXI;
        slabS[e + NXI] = xreg[k];
        if (lr == 0)  astoref(ghx_own + c, xreg[k]);
        if (lr == 11) astoref(ghx_own + NXI + c, xreg[k]);
      }
      sys_bar(flags, &bphase, tid, bs);  // R1
      for (int g = tid; g < 2 * NXI; g += NTHR) {
        const bool top = g < NXI;
        const int c = top ? g : g - NXI;
        if (top) { if (bs > 0)       slabS[c]            = aloadf(ghx + (size_t)(bs - 1) * 2 * NXI + NXI + c); }
        else     { if (bs < BPS - 1) slabS[13 * NXI + c] = aloadf(ghx + (size_t)(bs + 1) * 2 * NXI + c); }
      }
      __syncthreads();
#pragma unroll
      for (int k = 0; k < EPT; k++) {
        const int e = tid + k * NTHR;
        const int lr = e / NXI, c = e - lr * NXI;
        const int gr = gr0 + lr;
        const int ce = e + NXI;
        const float uc = xreg[k];
        const float um = (gr == 0)       ? uc : slabS[ce - NXI];
        const float ud = (gr == NXI - 1) ? uc : slabS[ce + NXI];
        const float ul = (c == 0)        ? uc : slabS[ce - 1];
        const float ur = (c == NXI - 1)  ? uc : slabS[ce + 1];
        treg[k] = mb - (cboo[ce] * uc + cbmo[ce] * um + cbom[ce] * ul + cbop[ce] * ur + cbpo[ce] * ud);
      }
      __syncthreads();  // all x reads done
      {
        double pp = 0;
#pragma unroll
        for (int k = 0; k < EPT; k++) {
          const int e = tid + k * NTHR;
          const int lr = e / NXI, c = e - lr * NXI;
          const float pn = treg[k];
          preg[k] = pn; rreg[k] = pn; r0reg[k] = pn;
          slabP[e + NXI] = pn;
          if (lr == 0)  astoref(ghq_own + c, pn);
          if (lr == 11) astoref(ghq_own + NXI + c, pn);
          pp += (double)pn * (double)pn;
        }
        bredN(&pp, 1, slots, 10, sys, bs, tid);
      }
      sys_bar(flags, &bphase, tid, bs);  // R2
      if (tid < 64) {
        double sp[1]; shredN(slots, 10, 1, sys, lane, sp);
        const float ra = froguard(sp[0]);
        if (lane == 0) { bcf[3] = ra; sh_r0abs = ra; }
      } else {
        for (int g = tid - 64; g < 2 * NXI; g += NTHR - 64) {
          const bool top = g < NXI;
          const int c = top ? g : g - NXI;
          const int ci = top ? c : 13 * NXI + c;
          if (top ? (bs > 0) : (bs < BPS - 1)) {
            const float pn = top ? aloadf(ghq + (size_t)(bs - 1) * 2 * NXI + NXI + c)
                                 : aloadf(ghq + (size_t)(bs + 1) * 2 * NXI + c);
            slabP[ci] = pn;
            rgh[g] = pn;
          }
        }
      }
      continue;   // loop-top syncthreads publishes bcf + slabs
    }

    const float alpha = bcf[0];
    if (code == 2) {
      // C3: x += alpha*p ; r = s (terminal: top breaks next round)
#pragma unroll
      for (int k = 0; k < EPT; k++) {
        xreg[k] = xreg[k] + alpha * preg[k];
        rreg[k] = rreg[k] - alpha * vreg[k];
      }
      continue;
    }

    // ---- s -> slabS (own rows + ghost rows from rgh - alpha*vgh) ----
#pragma unroll
    for (int k = 0; k < EPT; k++) {
      const int e = tid + k * NTHR;
      slabS[e + NXI] = rreg[k] - alpha * vreg[k];
    }
    for (int g = tid; g < 2 * NXI; g += NTHR) {
      const bool top = g < NXI;
      if (top ? (bs > 0) : (bs < BPS - 1)) {
        const int c = top ? g : g - NXI;
        const int ci = top ? c : 13 * NXI + c;
        slabS[ci] = rgh[g] - alpha * vgh[g];
      }
    }
    __syncthreads();
    // ---- t = A s ; publish t rows 0/11 ; 4 dots ----
    {
      double d[4] = {0, 0, 0, 0};
#pragma unroll
      for (int k = 0; k < EPT; k++) {
        const int e = tid + k * NTHR;
        const int lr = e / NXI, c = e - lr * NXI;
        const int gr = gr0 + lr;
        const int ce = e + NXI;
        const float sc = rreg[k] - alpha * vreg[k];
        const float um = (gr == 0)       ? sc : slabS[ce - NXI];
        const float ud = (gr == NXI - 1) ? sc : slabS[ce + NXI];
        const float ul = (c == 0)        ? sc : slabS[ce - 1];
        const float ur = (c == NXI - 1)  ? sc : slabS[ce + 1];
        const float tv = cboo[ce] * sc + cbmo[ce] * um + cbom[ce] * ul + cbop[ce] * ur + cbpo[ce] * ud;
        treg[k] = tv;
        if (lr == 0)  astoref(ght_own + c, tv);
        if (lr == 11) astoref(ght_own + NXI + c, tv);
        d[0] += (double)tv * (double)tv;          // <t,t>
        d[1] += (double)tv * (double)sc;          // <t,s>
        d[2] += (double)sc * (double)r0reg[k];    // <s,r0>
        d[3] += (double)tv * (double)r0reg[k];    // <t,r0>
      }
      bredN(d, 4, slots, 5, sys, bs, tid);
    }
    sys_bar(flags, &bphase, tid, bs);  // C

    // ==== P3: wave0 scalars || waves1-7 receive t ghosts; then update ====
    if (tid < 64) {
      double s2[4];
      shredN(slots, 5, 4, sys, lane, s2);
      const double tt = s2[0], ts = s2[1], sr0 = s2[2], tr0 = s2[3];
      const float om = (float)ts / (float)tt;
      const double dw = (double)om;
      const float rho_new = (float)(sr0 - dw * tr0);
      const double rr_new = sh_ss2 - 2.0 * dw * ts + dw * dw * tt;
      const float be = (bcf[0] / om) * (rho_new / sh_rho);
      if (lane == 0) {
        bcf[1] = om; bcf[2] = be; bcf[3] = froguard(rr_new);
      }
    } else {
      for (int g = tid - 64; g < 2 * NXI; g += NTHR - 64) {
        const bool top = g < NXI;
        const int c = top ? g : g - NXI;
        if (top) { if (bs > 0)       tgh[g] = aloadf(ght + (size_t)(bs - 1) * 2 * NXI + NXI + c); }
        else     { if (bs < BPS - 1) tgh[g] = aloadf(ght + (size_t)(bs + 1) * 2 * NXI + c); }
      }
    }
    __syncthreads();
    {
      const float omega = bcf[1];
      const float beta  = bcf[2];
#pragma unroll
      for (int k = 0; k < EPT; k++) {
        const int e = tid + k * NTHR;
        const float sc = rreg[k] - alpha * vreg[k];
        xreg[k] = xreg[k] + alpha * preg[k] + omega * sc;
        const float rn = sc - omega * treg[k];
        const float pn = rn + beta * (preg[k] - omega * vreg[k]);
        rreg[k] = rn;
        preg[k] = pn;
        slabP[e + NXI] = pn;
      }
      // ghost maintenance (rows -1, 12): bit-identical to neighbors' own rows
      for (int g = tid; g < 2 * NXI; g += NTHR) {
        const bool top = g < NXI;
        if (top ? (bs > 0) : (bs < BPS - 1)) {
          const int c = top ? g : g - NXI;
          const int ci = top ? c : 13 * NXI + c;
          const float sg = slabS[ci];
          const float rg_new = sg - omega * tgh[g];
          const float pg_new = rg_new + beta * (slabP[ci] - omega * vgh[g]);
          rgh[g] = rg_new;
          slabP[ci] = pg_new;
        }
      }
    }
    // no barrier: next P1 reads only block-local LDS (loop-top syncthreads)
  }

  // final write-out of x
#pragma unroll
  for (int k = 0; k < EPT; k++) {
    xs[tid + k * NTHR] = xreg[k];
  }
}

extern "C" void kernel_launch(void* const* d_in, const int* in_sizes, int n_in,
                              void* d_out, int out_size, void* d_ws, size_t ws_size,
                              hipStream_t stream) {
  const float* V  = (const float*)d_in[0];
  const float* M1 = (const float*)d_in[1];
  const float* M2 = (const float*)d_in[2];
  float* xout = (float*)d_out;
  float* wsf  = (float*)d_ws;
  hipMemsetAsync(d_ws, 0, 4096, stream);
  bicg_kernel<<<dim3(NBLK), dim3(NTHR), 0, stream>>>(V, M1, M2, xout, wsf);
}